// Round 2
// baseline (2706.129 us; speedup 1.0000x reference)
//
#include <hip/hip_runtime.h>
#include <math.h>

#define B_T   128
#define NS    128
#define NQ    512
#define DIN   256
#define DOUT  64

#define MU_SIZE  (B_T*NQ*DOUT)            // 4,194,304 floats
#define SIG_SIZE (B_T*NQ*DOUT*DOUT)       // 268,435,456 floats
#define NLL_IDX  (MU_SIZE + SIG_SIZE)     // 272,629,760

// ---------------------------------------------------------------------------
// K0a: Sp = A @ A^T  (fp64 accumulate); also zeroes the NLL accumulator.
// ---------------------------------------------------------------------------
__global__ __launch_bounds__(256) void k_prior_sp(const float* __restrict__ A,
                                                  double* __restrict__ Sp,
                                                  double* __restrict__ NLLACC) {
    __shared__ float Ai[16][260];
    __shared__ float Aj[16][260];
    int bi = blockIdx.x;
    int i0 = (bi >> 4) << 4;
    int j0 = (bi & 15) << 4;
    int tid = threadIdx.x;
    if (bi == 0 && tid == 0) NLLACC[0] = 0.0;
    for (int idx = tid; idx < 16 * 256; idx += 256) {
        int r = idx >> 8, c = idx & 255;
        Ai[r][c] = A[(i0 + r) * 256 + c];
        Aj[r][c] = A[(j0 + r) * 256 + c];
    }
    __syncthreads();
    int r = tid >> 4, c = tid & 15;
    double acc = 0.0;
    for (int k = 0; k < 256; ++k)
        acc += (double)Ai[r][k] * (double)Aj[c][k];
    Sp[(i0 + r) * 256 + (j0 + c)] = acc;
}

// ---------------------------------------------------------------------------
// K0b: MPN = Sp @ m_prior
// ---------------------------------------------------------------------------
__global__ __launch_bounds__(64) void k_prior_mpn(const double* __restrict__ Sp,
                                                  const float* __restrict__ MP,
                                                  double* __restrict__ MPN) {
    int i = blockIdx.x, k = threadIdx.x;
    double acc = 0.0;
    for (int t = 0; t < 256; ++t)
        acc += Sp[i * 256 + t] * (double)MP[t * 64 + k];
    MPN[i * 64 + k] = acc;
}

// ---------------------------------------------------------------------------
// K1: G_b = Phi_s^T Phi_s + Sp   (lower-triangle 64x64 tiles only, fp64)
// ---------------------------------------------------------------------------
__global__ __launch_bounds__(256) void k_build_G(const float* __restrict__ PHI,
                                                 const double* __restrict__ Sp,
                                                 double* __restrict__ G) {
    __shared__ float As[128][64];
    __shared__ float Bs[128][64];
    int b = blockIdx.x;
    int by = blockIdx.y;
    int ti = 0;
    while (((ti + 1) * (ti + 2)) / 2 <= by) ti++;
    int tj = by - (ti * (ti + 1)) / 2;
    int i0 = ti * 64, j0 = tj * 64;
    int tid = threadIdx.x;
    const float* Pb = PHI + b * (NS * DIN);
    for (int idx = tid; idx < 128 * 64; idx += 256) {
        int n = idx >> 6, c = idx & 63;
        As[n][c] = Pb[n * 256 + i0 + c];
        Bs[n][c] = Pb[n * 256 + j0 + c];
    }
    __syncthreads();
    int tx = tid & 15, ty = tid >> 4;
    double acc[4][4];
#pragma unroll
    for (int r = 0; r < 4; ++r)
#pragma unroll
        for (int s = 0; s < 4; ++s) acc[r][s] = 0.0;
    for (int n = 0; n < 128; ++n) {
        float a0 = As[n][4 * ty + 0], a1 = As[n][4 * ty + 1];
        float a2 = As[n][4 * ty + 2], a3 = As[n][4 * ty + 3];
        float b0 = Bs[n][4 * tx + 0], b1 = Bs[n][4 * tx + 1];
        float b2 = Bs[n][4 * tx + 2], b3 = Bs[n][4 * tx + 3];
        acc[0][0] += (double)a0 * b0; acc[0][1] += (double)a0 * b1;
        acc[0][2] += (double)a0 * b2; acc[0][3] += (double)a0 * b3;
        acc[1][0] += (double)a1 * b0; acc[1][1] += (double)a1 * b1;
        acc[1][2] += (double)a1 * b2; acc[1][3] += (double)a1 * b3;
        acc[2][0] += (double)a2 * b0; acc[2][1] += (double)a2 * b1;
        acc[2][2] += (double)a2 * b2; acc[2][3] += (double)a2 * b3;
        acc[3][0] += (double)a3 * b0; acc[3][1] += (double)a3 * b1;
        acc[3][2] += (double)a3 * b2; acc[3][3] += (double)a3 * b3;
    }
    double* Gb = G + b * 65536;
#pragma unroll
    for (int r = 0; r < 4; ++r) {
        int i = i0 + 4 * ty + r;
#pragma unroll
        for (int s = 0; s < 4; ++s) {
            int j = j0 + 4 * tx + s;
            Gb[i * 256 + j] = acc[r][s] + Sp[i * 256 + j];
        }
    }
}

// ---------------------------------------------------------------------------
// K2: RHS_b = Phi_s^T Y_s + MPN  (fp64)
// ---------------------------------------------------------------------------
__global__ __launch_bounds__(256) void k_build_rhs(const float* __restrict__ PHI,
                                                   const float* __restrict__ Y,
                                                   const double* __restrict__ MPN,
                                                   double* __restrict__ RHS) {
    __shared__ float As[128][64];
    __shared__ float Ys[128][64];
    int b = blockIdx.x, i0 = blockIdx.y * 64, tid = threadIdx.x;
    const float* Pb = PHI + b * (NS * DIN);
    const float* Yb = Y + b * (NS * DOUT);
    for (int idx = tid; idx < 128 * 64; idx += 256) {
        int n = idx >> 6, c = idx & 63;
        As[n][c] = Pb[n * 256 + i0 + c];
        Ys[n][c] = Yb[n * 64 + c];
    }
    __syncthreads();
    int tx = tid & 15, ty = tid >> 4;
    double acc[4][4];
#pragma unroll
    for (int r = 0; r < 4; ++r)
#pragma unroll
        for (int s = 0; s < 4; ++s) acc[r][s] = 0.0;
    for (int n = 0; n < 128; ++n) {
        float a0 = As[n][4 * ty + 0], a1 = As[n][4 * ty + 1];
        float a2 = As[n][4 * ty + 2], a3 = As[n][4 * ty + 3];
        float y0 = Ys[n][4 * tx + 0], y1 = Ys[n][4 * tx + 1];
        float y2 = Ys[n][4 * tx + 2], y3 = Ys[n][4 * tx + 3];
        acc[0][0] += (double)a0 * y0; acc[0][1] += (double)a0 * y1;
        acc[0][2] += (double)a0 * y2; acc[0][3] += (double)a0 * y3;
        acc[1][0] += (double)a1 * y0; acc[1][1] += (double)a1 * y1;
        acc[1][2] += (double)a1 * y2; acc[1][3] += (double)a1 * y3;
        acc[2][0] += (double)a2 * y0; acc[2][1] += (double)a2 * y1;
        acc[2][2] += (double)a2 * y2; acc[2][3] += (double)a2 * y3;
        acc[3][0] += (double)a3 * y0; acc[3][1] += (double)a3 * y1;
        acc[3][2] += (double)a3 * y2; acc[3][3] += (double)a3 * y3;
    }
    double* Rb = RHS + b * 16384;
#pragma unroll
    for (int r = 0; r < 4; ++r) {
        int i = i0 + 4 * ty + r;
#pragma unroll
        for (int s = 0; s < 4; ++s) {
            int kc = 4 * tx + s;
            Rb[i * 64 + kc] = acc[r][s] + MPN[i * 64 + kc];
        }
    }
}

// ---------------------------------------------------------------------------
// K3a: per-task blocked Cholesky (NB=16, in-place on G, writes LT[k*256+i]).
//      RESTRUCTURED: 1024 threads (4 waves/SIMD for latency hiding);
//      diag 16x16 factored by wave 0 via __shfl (no block barriers);
//      panel rows solved 1 thread/row; 3 barriers/panel instead of 32.
// ---------------------------------------------------------------------------
__global__ __launch_bounds__(1024) void k_chol(double* __restrict__ G,
                                               double* __restrict__ LT) {
    __shared__ double P[16 * 258];       // 33 KB panel
    __shared__ double L11s[16 * 17];     // factored diag block, row-major [j][p]
    __shared__ double DINVs[16];         // 1/diag
#define PCH(p, r) P[(p) * 258 + (r)]
    int b = blockIdx.x, tid = threadIdx.x;
    double* Gb = G + b * 65536;
    double* LTb = LT + b * 65536;
    for (int k0 = 0; k0 < 256; k0 += 16) {
        int rows = 256 - k0;
        // ---- stage panel: PCH(p, r) = Gb[r*256 + k0 + p], r in [k0,256) ----
        for (int idx = tid; idx < rows * 16; idx += 1024) {
            int r = k0 + (idx >> 4), p = idx & 15;
            PCH(p, r) = Gb[r * 256 + k0 + p];
        }
        __syncthreads();
        // ---- wave 0: factor the 16x16 diagonal block via shuffles ----
        if (tid < 64) {
            int lane = tid;
            double a[16];
            if (lane < 16) {
#pragma unroll
                for (int p = 0; p < 16; ++p) a[p] = PCH(p, k0 + lane);
            }
#pragma unroll
            for (int p = 0; p < 16; ++p) {
                double dp = __shfl(a[p], p);
                double d = sqrt(fmax(dp, 1e-300));
                double inv = 1.0 / d;
                if (lane == p) { a[p] = d; DINVs[p] = inv; }
                else if (lane > p) a[p] *= inv;
#pragma unroll
                for (int p2 = p + 1; p2 < 16; ++p2) {
                    double c = __shfl(a[p], p2);   // L[p2][p]
                    if (lane > p) a[p2] -= a[p] * c;
                }
            }
            if (lane < 16) {
#pragma unroll
                for (int p = 0; p < 16; ++p) {
                    if (p <= lane) {
                        L11s[lane * 17 + p] = a[p];
                        PCH(p, k0 + lane) = a[p];
                    }
                }
            }
        }
        __syncthreads();
        // ---- row-solve: thread t owns row r = k0+16+t;  x = L11^{-1} a ----
        if (tid < rows - 16) {
            int r = k0 + 16 + tid;
            double x[16];
#pragma unroll
            for (int p = 0; p < 16; ++p) {
                double s = PCH(p, r);
#pragma unroll
                for (int p2 = 0; p2 < 16; ++p2) {
                    if (p2 < p) s -= L11s[p * 17 + p2] * x[p2];
                }
                x[p] = s * DINVs[p];
                PCH(p, r) = x[p];
            }
        }
        __syncthreads();
        // ---- write finished panel to LT (coalesced along r) ----
        {
            int rr = tid & 255, pg = tid >> 8;   // pg in 0..3
#pragma unroll
            for (int p0 = 0; p0 < 16; p0 += 4) {
                int p = p0 + pg;
                int k = k0 + p;
                if (rr >= k) LTb[k * 256 + rr] = PCH(p, rr);
            }
        }
        // ---- trailing update: 2x2 microtile/thread, 128x32 region/pass ----
        int ty = tid >> 4, tx = tid & 15;        // ty in 0..63
        for (int i2 = k0 + 16 + 2 * ty; i2 < 256; i2 += 128) {
            double pa[16], pb[16];
#pragma unroll
            for (int p = 0; p < 16; ++p) { pa[p] = PCH(p, i2); pb[p] = PCH(p, i2 + 1); }
            for (int j2 = k0 + 16 + 2 * tx; j2 <= i2 + 1; j2 += 32) {
                double g00 = 0.0, g01 = 0.0, g10 = 0.0, g11 = 0.0;
#pragma unroll
                for (int p = 0; p < 16; ++p) {
                    double q0 = PCH(p, j2), q1 = PCH(p, j2 + 1);
                    g00 += pa[p] * q0; g01 += pa[p] * q1;
                    g10 += pb[p] * q0; g11 += pb[p] * q1;
                }
                if (j2 <= i2)     Gb[i2 * 256 + j2]           -= g00;
                if (j2 + 1 <= i2) Gb[i2 * 256 + j2 + 1]       -= g01;
                Gb[(i2 + 1) * 256 + j2] -= g10;               // j2 <= i2+1 by loop bound
                if (j2 <= i2)     Gb[(i2 + 1) * 256 + j2 + 1] -= g11;
            }
        }
        __syncthreads();
    }
#undef PCH
}

// ---------------------------------------------------------------------------
// K3b: zero upper triangle of TI/TIF; invert the 8 diagonal 32x32 blocks of L.
//      One block per task.
// ---------------------------------------------------------------------------
__global__ __launch_bounds__(256) void k_diaginv(const double* __restrict__ LT,
                                                 double* __restrict__ TI,
                                                 float* __restrict__ TIF) {
    __shared__ double SHD[8192];   // 8 diag blocks: SHD[g*1024 + k*32 + i] = L[32g+i][32g+k]
    int b = blockIdx.x, tid = threadIdx.x;
    const double* LTb = LT + b * 65536;
    double* TIb = TI + b * 65536;
    float* TIFb = TIF + b * 65536;
    for (int idx = tid; idx < 65536; idx += 256) {
        int i = idx >> 8, k = idx & 255;
        if (k > i) { TIb[idx] = 0.0; TIFb[idx] = 0.0f; }
    }
    for (int idx = tid; idx < 8192; idx += 256) {
        int g = idx >> 10, rem = idx & 1023, k = rem >> 5, i = rem & 31;
        SHD[idx] = LTb[(32 * g + k) * 256 + 32 * g + i];
    }
    __syncthreads();
    int g = tid >> 5, j = tid & 31;
    const double* D = SHD + g * 1024;       // D[k*32+i] = L[i][k]
    double x[32];
#pragma unroll
    for (int i = 0; i < 32; ++i) {
        double s = (i == j) ? 1.0 : 0.0;
#pragma unroll
        for (int k = 0; k < i; ++k) {
            double lv = D[k * 32 + i];
            s -= (k >= j) ? lv * x[k] : 0.0;
        }
        double inv = 1.0 / D[i * 32 + i];
        x[i] = (i >= j) ? s * inv : 0.0;
    }
#pragma unroll
    for (int i = 0; i < 32; ++i) {
        int gi = 32 * g + i, gj = 32 * g + j;
        TIb[gi * 256 + gj] = x[i];
        TIFb[gi * 256 + gj] = (float)x[i];
    }
}

// ---------------------------------------------------------------------------
// K3c: off-diagonal trinv sweep, COLUMN-BLOCK PARALLEL.
//      grid = (B, 7): block (b, J) computes X_IJ for I = J+1..7 where
//      X_IJ = -TinvII * (sum_{K=J}^{I-1} L_IK @ X_KJ).
// ---------------------------------------------------------------------------
__global__ __launch_bounds__(256) void k_trinv(const double* __restrict__ LT,
                                               double* __restrict__ TI,
                                               float* __restrict__ TIF) {
    __shared__ double XS[8][1024];   // XS[K][kk*32+j] = X[32K+kk][32J+j]; XS[7] = Bsh/Lsh
    int b = blockIdx.x, J = blockIdx.y;      // J in 0..6
    int tid = threadIdx.x, j = tid & 31, ig = tid >> 5;
    const double* LTb = LT + b * 65536;
    double* TIb = TI + b * 65536;
    float* TIFb = TIF + b * 65536;
    double* Bsh = XS[7];                      // scratch: staged L tile / C tile

    // preload X_JJ (diag inverse) into the column cache
    for (int idx = tid; idx < 1024; idx += 256) {
        int kk = idx >> 5, c = idx & 31;
        XS[J][idx] = TIb[(32 * J + kk) * 256 + 32 * J + c];
    }
    __syncthreads();

    for (int I = J + 1; I < 8; ++I) {
        double acc[4] = {0.0, 0.0, 0.0, 0.0};
        for (int K = J; K < I; ++K) {
            // stage L_IK: Lsh[kk*32+i2] = L[32I+i2][32K+kk]  (coalesced in i2)
            for (int idx = tid; idx < 1024; idx += 256) {
                int kk = idx >> 5, i2 = idx & 31;
                Bsh[idx] = LTb[(32 * K + kk) * 256 + 32 * I + i2];
            }
            __syncthreads();
            const double* Xk = XS[K];
            for (int kk = 0; kk < 32; ++kk) {
                double tv = Xk[kk * 32 + j];
#pragma unroll
                for (int r = 0; r < 4; ++r)
                    acc[r] += Bsh[kk * 32 + ig * 4 + r] * tv;
            }
            __syncthreads();   // protect Bsh before next stage / C write
        }
        // C tile -> Bsh
#pragma unroll
        for (int r = 0; r < 4; ++r) Bsh[(ig * 4 + r) * 32 + j] = acc[r];
        __syncthreads();
        // X_IJ = -TinvII @ C
        double c[4] = {0.0, 0.0, 0.0, 0.0};
        for (int k = 0; k < 32; ++k) {
            double bv = Bsh[k * 32 + j];
#pragma unroll
            for (int r = 0; r < 4; ++r)
                c[r] -= TIb[(32 * I + ig * 4 + r) * 256 + 32 * I + k] * bv;
        }
#pragma unroll
        for (int r = 0; r < 4; ++r) {
            int gi = 32 * I + ig * 4 + r, gj = 32 * J + j;
            TIb[gi * 256 + gj] = c[r];
            TIFb[gi * 256 + gj] = (float)c[r];
            if (I < 7) XS[I][(ig * 4 + r) * 32 + j] = c[r];
        }
        __syncthreads();   // Bsh reads done + XS[I] visible before next I
    }
}

// ---------------------------------------------------------------------------
// K4a: Z = Tinv @ RHS  (fp64 tiled GEMM, triangular k-skip)
// ---------------------------------------------------------------------------
__global__ __launch_bounds__(256) void k_gemm_Z(const double* __restrict__ TI,
                                                const double* __restrict__ RHS,
                                                double* __restrict__ Z) {
    __shared__ double As[32][64];
    __shared__ double Bs[64][64];
    int b = blockIdx.x, i0 = blockIdx.y * 32;
    int tid = threadIdx.x, c = tid & 63, rg = tid >> 6;
    const double* TIb = TI + b * 65536;
    const double* Rb = RHS + b * 16384;
    double* Zb = Z + b * 16384;
    double acc[8] = {};
    for (int k0 = 0; k0 <= i0; k0 += 64) {
        for (int idx = tid; idx < 2048; idx += 256) {
            int r = idx >> 6, kk = idx & 63;
            As[r][kk] = TIb[(i0 + r) * 256 + k0 + kk];
        }
        for (int idx = tid; idx < 4096; idx += 256) {
            int kk = idx >> 6, cc = idx & 63;
            Bs[kk][cc] = Rb[(k0 + kk) * 64 + cc];
        }
        __syncthreads();
        for (int kk = 0; kk < 64; ++kk) {
            double bv = Bs[kk][c];
#pragma unroll
            for (int r = 0; r < 8; ++r)
                acc[r] += As[rg * 8 + r][kk] * bv;
        }
        __syncthreads();
    }
#pragma unroll
    for (int r = 0; r < 8; ++r)
        Zb[(i0 + rg * 8 + r) * 64 + c] = acc[r];
}

// ---------------------------------------------------------------------------
// K4b: M = Tinv^T @ Z  (fp64 tiled GEMM, triangular k-skip), M -> RHS buffer
// ---------------------------------------------------------------------------
__global__ __launch_bounds__(256) void k_gemm_M(const double* __restrict__ TI,
                                                const double* __restrict__ Z,
                                                double* __restrict__ M) {
    __shared__ double As[64][32];
    __shared__ double Bs[64][64];
    int b = blockIdx.x, i0 = blockIdx.y * 32;
    int tid = threadIdx.x, c = tid & 63, rg = tid >> 6;
    const double* TIb = TI + b * 65536;
    const double* Zb = Z + b * 16384;
    double* Mb = M + b * 16384;
    double acc[8] = {};
    for (int k0 = (i0 >> 6) << 6; k0 < 256; k0 += 64) {
        for (int idx = tid; idx < 2048; idx += 256) {
            int kk = idx >> 5, ri = idx & 31;
            As[kk][ri] = TIb[(k0 + kk) * 256 + i0 + ri];
        }
        for (int idx = tid; idx < 4096; idx += 256) {
            int kk = idx >> 6, cc = idx & 63;
            Bs[kk][cc] = Zb[(k0 + kk) * 64 + cc];
        }
        __syncthreads();
        for (int kk = 0; kk < 64; ++kk) {
            double bv = Bs[kk][c];
#pragma unroll
            for (int r = 0; r < 8; ++r)
                acc[r] += As[kk][rg * 8 + r] * bv;
        }
        __syncthreads();
    }
#pragma unroll
    for (int r = 0; r < 8; ++r)
        Mb[(i0 + rg * 8 + r) * 64 + c] = acc[r];
}

// ---------------------------------------------------------------------------
// K5: W = PhiQ @ TinvF^T, PSUM[b][I][q] = sum_{i in I-tile} W[q][i]^2 (fp32)
// ---------------------------------------------------------------------------
__global__ __launch_bounds__(256) void k_spread_gemm(const float* __restrict__ PHIQ,
                                                     const float* __restrict__ TIF,
                                                     float* __restrict__ PSUM) {
    __shared__ float Qs[64][65];   // [q][k]
    __shared__ float Ts[64][65];   // [k][i]
    int b = blockIdx.x, q0 = blockIdx.y * 64, I = blockIdx.z, i0 = I * 64;
    int tid = threadIdx.x, tx = tid & 15, ty = tid >> 4;
    const float* Qb = PHIQ + b * (NQ * DIN) + q0 * DIN;
    const float* Tb = TIF + b * 65536;
    float acc[4][4];
#pragma unroll
    for (int r = 0; r < 4; ++r)
#pragma unroll
        for (int s = 0; s < 4; ++s) acc[r][s] = 0.0f;
    for (int k0 = 0; k0 <= i0; k0 += 64) {
        for (int idx = tid; idx < 4096; idx += 256) {
            int r = idx >> 6, c = idx & 63;
            Qs[r][c] = Qb[r * 256 + k0 + c];
            Ts[c][r] = Tb[(i0 + r) * 256 + k0 + c];
        }
        __syncthreads();
        for (int kk = 0; kk < 64; ++kk) {
            float a0 = Qs[4 * ty + 0][kk], a1 = Qs[4 * ty + 1][kk];
            float a2 = Qs[4 * ty + 2][kk], a3 = Qs[4 * ty + 3][kk];
            float b0 = Ts[kk][4 * tx + 0], b1 = Ts[kk][4 * tx + 1];
            float b2 = Ts[kk][4 * tx + 2], b3 = Ts[kk][4 * tx + 3];
            acc[0][0] += a0 * b0; acc[0][1] += a0 * b1; acc[0][2] += a0 * b2; acc[0][3] += a0 * b3;
            acc[1][0] += a1 * b0; acc[1][1] += a1 * b1; acc[1][2] += a1 * b2; acc[1][3] += a1 * b3;
            acc[2][0] += a2 * b0; acc[2][1] += a2 * b1; acc[2][2] += a2 * b2; acc[2][3] += a2 * b3;
            acc[3][0] += a3 * b0; acc[3][1] += a3 * b1; acc[3][2] += a3 * b2; acc[3][3] += a3 * b3;
        }
        __syncthreads();
    }
#pragma unroll
    for (int r = 0; r < 4; ++r) {
        float p = acc[r][0] * acc[r][0] + acc[r][1] * acc[r][1]
                + acc[r][2] * acc[r][2] + acc[r][3] * acc[r][3];
        p += __shfl_down(p, 8, 16);
        p += __shfl_down(p, 4, 16);
        p += __shfl_down(p, 2, 16);
        p += __shfl_down(p, 1, 16);
        if (tx == 0) PSUM[(size_t)(b * 4 + I) * 512 + q0 + 4 * ty + r] = p;
    }
}

// ---------------------------------------------------------------------------
// K6: mu = Phi_q @ m (fp32), FUSED epilogue: spread combine -> SPREAD,
//     nll partial (resid^2, logs) -> one fp64 atomicAdd per block.
// ---------------------------------------------------------------------------
__global__ __launch_bounds__(256) void k_mu_nll(const float* __restrict__ PHIQ,
                                                const double* __restrict__ M,
                                                const float* __restrict__ YQ,
                                                const float* __restrict__ PSUM,
                                                const float* __restrict__ SE,
                                                float* __restrict__ SPREAD,
                                                double* __restrict__ NLLACC,
                                                float* __restrict__ MU) {
    __shared__ float Qs[64][65];
    __shared__ float Ms[64][64];
    __shared__ double nred[64];
    int b = blockIdx.x, q0 = blockIdx.y * 64, tid = threadIdx.x;
    int tx = tid & 15, ty = tid >> 4;
    const float* Qb = PHIQ + b * (NQ * DIN) + q0 * DIN;
    const double* Mb = M + b * 16384;
    float acc[4][4];
#pragma unroll
    for (int r = 0; r < 4; ++r)
#pragma unroll
        for (int s = 0; s < 4; ++s) acc[r][s] = 0.0f;
    for (int c0 = 0; c0 < 256; c0 += 64) {
        for (int idx = tid; idx < 4096; idx += 256) {
            int r = idx >> 6, c = idx & 63;
            Qs[r][c] = Qb[r * 256 + c0 + c];
            Ms[r][c] = (float)Mb[(c0 + r) * 64 + c];
        }
        __syncthreads();
        for (int kk = 0; kk < 64; ++kk) {
            float a0 = Qs[4 * ty + 0][kk], a1 = Qs[4 * ty + 1][kk];
            float a2 = Qs[4 * ty + 2][kk], a3 = Qs[4 * ty + 3][kk];
            float b0 = Ms[kk][4 * tx + 0], b1 = Ms[kk][4 * tx + 1];
            float b2 = Ms[kk][4 * tx + 2], b3 = Ms[kk][4 * tx + 3];
            acc[0][0] += a0 * b0; acc[0][1] += a0 * b1; acc[0][2] += a0 * b2; acc[0][3] += a0 * b3;
            acc[1][0] += a1 * b0; acc[1][1] += a1 * b1; acc[1][2] += a1 * b2; acc[1][3] += a1 * b3;
            acc[2][0] += a2 * b0; acc[2][1] += a2 * b1; acc[2][2] += a2 * b2; acc[2][3] += a2 * b3;
            acc[3][0] += a3 * b0; acc[3][1] += a3 * b1; acc[3][2] += a3 * b2; acc[3][3] += a3 * b3;
        }
        __syncthreads();
    }
    float se = SE[0];
#pragma unroll
    for (int r = 0; r < 4; ++r) {
        int q = q0 + 4 * ty + r;
        float4 v = make_float4(acc[r][0], acc[r][1], acc[r][2], acc[r][3]);
        *(float4*)&MU[(b * NQ + q) * 64 + 4 * tx] = v;
        // nll partial for this row
        float4 y = *(const float4*)&YQ[(size_t)(b * NQ + q) * 64 + 4 * tx];
        float dx = y.x - v.x, dy = y.y - v.y, dz = y.z - v.z, dw = y.w - v.w;
        float qs = dx * dx + dy * dy + dz * dz + dw * dw;
        qs += __shfl_down(qs, 8, 16);
        qs += __shfl_down(qs, 4, 16);
        qs += __shfl_down(qs, 2, 16);
        qs += __shfl_down(qs, 1, 16);
        if (tx == 0) {
            float sp = 1.0f + PSUM[(size_t)(b * 4 + 0) * 512 + q]
                            + PSUM[(size_t)(b * 4 + 1) * 512 + q]
                            + PSUM[(size_t)(b * 4 + 2) * 512 + q]
                            + PSUM[(size_t)(b * 4 + 3) * 512 + q];
            SPREAD[b * 512 + q] = sp;
            float val = 64.0f * (logf(sp) + logf(se)) + qs / (sp * se);
            nred[ty * 4 + r] = (double)val;
        }
    }
    __syncthreads();
    for (int s = 32; s > 0; s >>= 1) {
        if (tid < s) nred[tid] += nred[tid + s];
        __syncthreads();
    }
    if (tid == 0) atomicAdd(NLLACC, nred[0] * (1.0 / 65536.0));
}

// ---------------------------------------------------------------------------
// K6b: write nll scalar
// ---------------------------------------------------------------------------
__global__ void k_nll_final(const double* __restrict__ NLLACC,
                            float* __restrict__ out) {
    if (threadIdx.x == 0) out[NLL_IDX] = (float)NLLACC[0];
}

// ---------------------------------------------------------------------------
// K7 (runs LAST): stream sig; fully overwrites scratch inside d_out sig region.
// ---------------------------------------------------------------------------
__global__ __launch_bounds__(256) void k_sig(const float* __restrict__ SPREAD,
                                             const float* __restrict__ SE,
                                             float* __restrict__ out) {
    __shared__ float sv_s;
    int bq = blockIdx.x, tid = threadIdx.x;
    if (tid == 0) sv_s = SPREAD[bq] * SE[0];
    __syncthreads();
    float sv = sv_s;
    float* base = out + (size_t)MU_SIZE + (size_t)bq * 4096;
    int i = tid >> 2;
    int jb = (tid & 3) << 4;
    int d = i - jb;
    float vals[16];
#pragma unroll
    for (int t = 0; t < 16; ++t) vals[t] = (t == d) ? sv : 0.0f;
    float4* p = (float4*)(base + tid * 16);
    p[0] = make_float4(vals[0], vals[1], vals[2], vals[3]);
    p[1] = make_float4(vals[4], vals[5], vals[6], vals[7]);
    p[2] = make_float4(vals[8], vals[9], vals[10], vals[11]);
    p[3] = make_float4(vals[12], vals[13], vals[14], vals[15]);
}

// ---------------------------------------------------------------------------
extern "C" void kernel_launch(void* const* d_in, const int* in_sizes, int n_in,
                              void* d_out, int out_size, void* d_ws, size_t ws_size,
                              hipStream_t stream) {
    const float* PHI_S = (const float*)d_in[0];
    const float* Y_S   = (const float*)d_in[1];
    const float* PHI_Q = (const float*)d_in[2];
    const float* Y_Q   = (const float*)d_in[3];
    const float* MP    = (const float*)d_in[4];
    const float* AP    = (const float*)d_in[5];
    const float* SE    = (const float*)d_in[6];
    float* out = (float*)d_out;

    // Big scratch inside sig region of d_out (dead before k_sig runs last).
    double* scratch = (double*)(out + MU_SIZE);
    double* G    = scratch;                    // 8,388,608 dbl (64 MB)
    double* LT   = G + 8388608;                // 8,388,608 dbl
    double* RHS  = LT + 8388608;               // 2,097,152 dbl (-> becomes M)
    double* Z    = RHS + 2097152;              // 2,097,152 dbl
    double* TI   = Z + 2097152;                // 8,388,608 dbl
    double* Spd  = TI + 8388608;               // 65,536 dbl
    double* MPN  = Spd + 65536;                // 16,384 dbl
    float*  TIF  = (float*)(MPN + 16384);      // 8,388,608 f32 (32 MB)
    float*  PSUM = TIF + 8388608;              // 262,144 f32 (1 MB)
    // Small persistent scratch (survives until k_sig) in d_ws (proven 258 KB).
    float*  SPREAD = (float*)d_ws;                        // 65,536 f32
    double* NLLACC = (double*)((char*)d_ws + 65536 * 4);  // 1 dbl

    k_prior_sp   <<<256, 256, 0, stream>>>(AP, Spd, NLLACC);
    k_prior_mpn  <<<256, 64, 0, stream>>>(Spd, MP, MPN);
    k_build_G    <<<dim3(B_T, 10), 256, 0, stream>>>(PHI_S, Spd, G);
    k_build_rhs  <<<dim3(B_T, 4), 256, 0, stream>>>(PHI_S, Y_S, MPN, RHS);
    k_chol       <<<B_T, 1024, 0, stream>>>(G, LT);
    k_diaginv    <<<B_T, 256, 0, stream>>>(LT, TI, TIF);
    k_trinv      <<<dim3(B_T, 7), 256, 0, stream>>>(LT, TI, TIF);
    k_gemm_Z     <<<dim3(B_T, 8), 256, 0, stream>>>(TI, RHS, Z);
    k_gemm_M     <<<dim3(B_T, 8), 256, 0, stream>>>(TI, Z, RHS);
    k_spread_gemm<<<dim3(B_T, 8, 4), 256, 0, stream>>>(PHI_Q, TIF, PSUM);
    k_mu_nll     <<<dim3(B_T, 8), 256, 0, stream>>>(PHI_Q, RHS, Y_Q, PSUM, SE,
                                                    SPREAD, NLLACC, out);
    k_nll_final  <<<1, 64, 0, stream>>>(NLLACC, out);
    k_sig        <<<65536, 256, 0, stream>>>(SPREAD, SE, out);   // LAST
}

// Round 3
// 2307.978 us; speedup vs baseline: 1.1725x; 1.1725x over previous
//
#include <hip/hip_runtime.h>
#include <math.h>

#define B_T   128
#define NS    128
#define NQ    512
#define DIN   256
#define DOUT  64

#define MU_SIZE  (B_T*NQ*DOUT)            // 4,194,304 floats
#define SIG_SIZE (B_T*NQ*DOUT*DOUT)       // 268,435,456 floats
#define NLL_IDX  (MU_SIZE + SIG_SIZE)     // 272,629,760

// ---------------------------------------------------------------------------
// K0a: Sp = A @ A^T  (fp64 accumulate); also zeroes the NLL accumulator.
// ---------------------------------------------------------------------------
__global__ __launch_bounds__(256) void k_prior_sp(const float* __restrict__ A,
                                                  double* __restrict__ Sp,
                                                  double* __restrict__ NLLACC) {
    __shared__ float Ai[16][260];
    __shared__ float Aj[16][260];
    int bi = blockIdx.x;
    int i0 = (bi >> 4) << 4;
    int j0 = (bi & 15) << 4;
    int tid = threadIdx.x;
    if (bi == 0 && tid == 0) NLLACC[0] = 0.0;
    for (int idx = tid; idx < 16 * 256; idx += 256) {
        int r = idx >> 8, c = idx & 255;
        Ai[r][c] = A[(i0 + r) * 256 + c];
        Aj[r][c] = A[(j0 + r) * 256 + c];
    }
    __syncthreads();
    int r = tid >> 4, c = tid & 15;
    double acc = 0.0;
    for (int k = 0; k < 256; ++k)
        acc += (double)Ai[r][k] * (double)Aj[c][k];
    Sp[(i0 + r) * 256 + (j0 + c)] = acc;
}

// ---------------------------------------------------------------------------
// K0b: MPN = Sp @ m_prior
// ---------------------------------------------------------------------------
__global__ __launch_bounds__(64) void k_prior_mpn(const double* __restrict__ Sp,
                                                  const float* __restrict__ MP,
                                                  double* __restrict__ MPN) {
    int i = blockIdx.x, k = threadIdx.x;
    double acc = 0.0;
    for (int t = 0; t < 256; ++t)
        acc += Sp[i * 256 + t] * (double)MP[t * 64 + k];
    MPN[i * 64 + k] = acc;
}

// ---------------------------------------------------------------------------
// K1: G_b = Phi_s^T Phi_s + Sp   (lower-triangle 64x64 tiles only, fp64)
// ---------------------------------------------------------------------------
__global__ __launch_bounds__(256) void k_build_G(const float* __restrict__ PHI,
                                                 const double* __restrict__ Sp,
                                                 double* __restrict__ G) {
    __shared__ float As[128][64];
    __shared__ float Bs[128][64];
    int b = blockIdx.x;
    int by = blockIdx.y;
    int ti = 0;
    while (((ti + 1) * (ti + 2)) / 2 <= by) ti++;
    int tj = by - (ti * (ti + 1)) / 2;
    int i0 = ti * 64, j0 = tj * 64;
    int tid = threadIdx.x;
    const float* Pb = PHI + b * (NS * DIN);
    for (int idx = tid; idx < 128 * 64; idx += 256) {
        int n = idx >> 6, c = idx & 63;
        As[n][c] = Pb[n * 256 + i0 + c];
        Bs[n][c] = Pb[n * 256 + j0 + c];
    }
    __syncthreads();
    int tx = tid & 15, ty = tid >> 4;
    double acc[4][4];
#pragma unroll
    for (int r = 0; r < 4; ++r)
#pragma unroll
        for (int s = 0; s < 4; ++s) acc[r][s] = 0.0;
    for (int n = 0; n < 128; ++n) {
        float a0 = As[n][4 * ty + 0], a1 = As[n][4 * ty + 1];
        float a2 = As[n][4 * ty + 2], a3 = As[n][4 * ty + 3];
        float b0 = Bs[n][4 * tx + 0], b1 = Bs[n][4 * tx + 1];
        float b2 = Bs[n][4 * tx + 2], b3 = Bs[n][4 * tx + 3];
        acc[0][0] += (double)a0 * b0; acc[0][1] += (double)a0 * b1;
        acc[0][2] += (double)a0 * b2; acc[0][3] += (double)a0 * b3;
        acc[1][0] += (double)a1 * b0; acc[1][1] += (double)a1 * b1;
        acc[1][2] += (double)a1 * b2; acc[1][3] += (double)a1 * b3;
        acc[2][0] += (double)a2 * b0; acc[2][1] += (double)a2 * b1;
        acc[2][2] += (double)a2 * b2; acc[2][3] += (double)a2 * b3;
        acc[3][0] += (double)a3 * b0; acc[3][1] += (double)a3 * b1;
        acc[3][2] += (double)a3 * b2; acc[3][3] += (double)a3 * b3;
    }
    double* Gb = G + b * 65536;
#pragma unroll
    for (int r = 0; r < 4; ++r) {
        int i = i0 + 4 * ty + r;
#pragma unroll
        for (int s = 0; s < 4; ++s) {
            int j = j0 + 4 * tx + s;
            Gb[i * 256 + j] = acc[r][s] + Sp[i * 256 + j];
        }
    }
}

// ---------------------------------------------------------------------------
// K2: RHS_b = Phi_s^T Y_s + MPN  (fp64)
// ---------------------------------------------------------------------------
__global__ __launch_bounds__(256) void k_build_rhs(const float* __restrict__ PHI,
                                                   const float* __restrict__ Y,
                                                   const double* __restrict__ MPN,
                                                   double* __restrict__ RHS) {
    __shared__ float As[128][64];
    __shared__ float Ys[128][64];
    int b = blockIdx.x, i0 = blockIdx.y * 64, tid = threadIdx.x;
    const float* Pb = PHI + b * (NS * DIN);
    const float* Yb = Y + b * (NS * DOUT);
    for (int idx = tid; idx < 128 * 64; idx += 256) {
        int n = idx >> 6, c = idx & 63;
        As[n][c] = Pb[n * 256 + i0 + c];
        Ys[n][c] = Yb[n * 64 + c];
    }
    __syncthreads();
    int tx = tid & 15, ty = tid >> 4;
    double acc[4][4];
#pragma unroll
    for (int r = 0; r < 4; ++r)
#pragma unroll
        for (int s = 0; s < 4; ++s) acc[r][s] = 0.0;
    for (int n = 0; n < 128; ++n) {
        float a0 = As[n][4 * ty + 0], a1 = As[n][4 * ty + 1];
        float a2 = As[n][4 * ty + 2], a3 = As[n][4 * ty + 3];
        float y0 = Ys[n][4 * tx + 0], y1 = Ys[n][4 * tx + 1];
        float y2 = Ys[n][4 * tx + 2], y3 = Ys[n][4 * tx + 3];
        acc[0][0] += (double)a0 * y0; acc[0][1] += (double)a0 * y1;
        acc[0][2] += (double)a0 * y2; acc[0][3] += (double)a0 * y3;
        acc[1][0] += (double)a1 * y0; acc[1][1] += (double)a1 * y1;
        acc[1][2] += (double)a1 * y2; acc[1][3] += (double)a1 * y3;
        acc[2][0] += (double)a2 * y0; acc[2][1] += (double)a2 * y1;
        acc[2][2] += (double)a2 * y2; acc[2][3] += (double)a2 * y3;
        acc[3][0] += (double)a3 * y0; acc[3][1] += (double)a3 * y1;
        acc[3][2] += (double)a3 * y2; acc[3][3] += (double)a3 * y3;
    }
    double* Rb = RHS + b * 16384;
#pragma unroll
    for (int r = 0; r < 4; ++r) {
        int i = i0 + 4 * ty + r;
#pragma unroll
        for (int s = 0; s < 4; ++s) {
            int kc = 4 * tx + s;
            Rb[i * 64 + kc] = acc[r][s] + MPN[i * 64 + kc];
        }
    }
}

// ---------------------------------------------------------------------------
// K3a: per-task LEFT-LOOKING blocked Cholesky (NB=16).
//      G is read ONCE and never written (no trailing RMW). Per panel:
//      W[r][p] = sum_{c<k0} L[r,c]*L[k0+p,c]  (streaming GEMM, coalesced LT
//      column reads, 16-row L slice cached in LDS, 2-way K-split over halves),
//      subtract once from staged G panel in LDS, factor diag via wave-0 shfl,
//      parallel row-solve, write LT panel coalesced. 512 threads.
// ---------------------------------------------------------------------------
__global__ __launch_bounds__(512) void k_chol(const double* __restrict__ G,
                                              double* __restrict__ LT) {
    __shared__ double P[16 * 258];       // panel PCH(p,r), 33 KB
    __shared__ double Ls[240 * 16];      // Ls[c*16+p] = L[k0+p][c], 30.7 KB
    __shared__ double Wp[256 * 17];      // half-1 partial W, padded, 34.8 KB
    __shared__ double L11s[16 * 17];     // factored diag block, row-major [j][p]
    __shared__ double DINVs[16];         // 1/diag
#define PCH(p, r) P[(p) * 258 + (r)]
    int b = blockIdx.x, tid = threadIdx.x;
    const double* Gb = G + b * 65536;
    double* LTb = LT + b * 65536;
    int rowt = tid & 255, h = tid >> 8;   // h: K-split half
    for (int k0 = 0; k0 < 256; k0 += 16) {
        int m = 256 - k0;
        // ---- stage prior-L slice (Ls) and G panel (P), coalesced ----
        for (int idx = tid; idx < k0 * 16; idx += 512) {
            int c = idx >> 4, p = idx & 15;
            Ls[c * 16 + p] = LTb[c * 256 + k0 + p];
        }
        for (int idx = tid; idx < m * 16; idx += 512) {
            int rr = k0 + (idx >> 4), p = idx & 15;
            PCH(p, rr) = Gb[rr * 256 + k0 + p];
        }
        __syncthreads();
        // ---- W-GEMM in registers: thread owns row r, half h of c-range ----
        int r = k0 + rowt;
        double W[16];
#pragma unroll
        for (int p = 0; p < 16; ++p) W[p] = 0.0;
        if (rowt < m && k0 > 0) {
            int csplit = k0 >> 1;
            int cb = h ? csplit : 0;
            int ce = h ? k0 : csplit;
            const double* lrow = LTb + r;          // LTb[c*256 + r], coalesced
#pragma unroll 2
            for (int c = cb; c < ce; ++c) {
                double lv = lrow[c * 256];
                const double2* lsc = (const double2*)(Ls + c * 16);
#pragma unroll
                for (int u = 0; u < 8; ++u) {
                    double2 lw = lsc[u];
                    W[2 * u]     += lv * lw.x;
                    W[2 * u + 1] += lv * lw.y;
                }
            }
        }
        if (h == 1 && rowt < m) {
#pragma unroll
            for (int p = 0; p < 16; ++p) Wp[rowt * 17 + p] = W[p];
        }
        __syncthreads();
        // ---- combine halves, subtract from panel ----
        if (h == 0 && rowt < m) {
#pragma unroll
            for (int p = 0; p < 16; ++p)
                PCH(p, r) -= W[p] + Wp[rowt * 17 + p];
        }
        __syncthreads();
        // ---- wave 0: factor the 16x16 diagonal block via shuffles ----
        if (tid < 64) {
            int lane = tid;
            double a[16];
            if (lane < 16) {
#pragma unroll
                for (int p = 0; p < 16; ++p) a[p] = PCH(p, k0 + lane);
            }
#pragma unroll
            for (int p = 0; p < 16; ++p) {
                double dp = __shfl(a[p], p);
                double d = sqrt(fmax(dp, 1e-300));
                double inv = 1.0 / d;
                if (lane == p) { a[p] = d; DINVs[p] = inv; }
                else if (lane > p) a[p] *= inv;
#pragma unroll
                for (int p2 = p + 1; p2 < 16; ++p2) {
                    double c = __shfl(a[p], p2);   // L[p2][p]
                    if (lane > p) a[p2] -= a[p] * c;
                }
            }
            if (lane < 16) {
#pragma unroll
                for (int p = 0; p < 16; ++p) {
                    if (p <= lane) {
                        L11s[lane * 17 + p] = a[p];
                        PCH(p, k0 + lane) = a[p];
                    }
                }
            }
        }
        __syncthreads();
        // ---- row-solve: thread t owns row rr = k0+16+t;  x = L11^{-1} a ----
        if (tid < m - 16) {
            int rr = k0 + 16 + tid;
            double x[16];
#pragma unroll
            for (int p = 0; p < 16; ++p) {
                double s = PCH(p, rr);
#pragma unroll
                for (int p2 = 0; p2 < 16; ++p2) {
                    if (p2 < p) s -= L11s[p * 17 + p2] * x[p2];
                }
                x[p] = s * DINVs[p];
                PCH(p, rr) = x[p];
            }
        }
        __syncthreads();
        // ---- write finished panel to LT (coalesced along r) ----
        {
            int rr2 = tid & 255, pg = tid >> 8;
#pragma unroll
            for (int p0 = 0; p0 < 16; p0 += 2) {
                int p = p0 + pg;
                int k = k0 + p;
                if (rr2 >= k) LTb[k * 256 + rr2] = PCH(p, rr2);
            }
        }
        __syncthreads();   // LT visible before next panel's Ls stage
    }
#undef PCH
}

// ---------------------------------------------------------------------------
// K3b: zero upper triangle of TI/TIF; invert the 8 diagonal 32x32 blocks of L.
//      One block per task.
// ---------------------------------------------------------------------------
__global__ __launch_bounds__(256) void k_diaginv(const double* __restrict__ LT,
                                                 double* __restrict__ TI,
                                                 float* __restrict__ TIF) {
    __shared__ double SHD[8192];   // 8 diag blocks: SHD[g*1024 + k*32 + i] = L[32g+i][32g+k]
    int b = blockIdx.x, tid = threadIdx.x;
    const double* LTb = LT + b * 65536;
    double* TIb = TI + b * 65536;
    float* TIFb = TIF + b * 65536;
    for (int idx = tid; idx < 65536; idx += 256) {
        int i = idx >> 8, k = idx & 255;
        if (k > i) { TIb[idx] = 0.0; TIFb[idx] = 0.0f; }
    }
    for (int idx = tid; idx < 8192; idx += 256) {
        int g = idx >> 10, rem = idx & 1023, k = rem >> 5, i = rem & 31;
        SHD[idx] = LTb[(32 * g + k) * 256 + 32 * g + i];
    }
    __syncthreads();
    int g = tid >> 5, j = tid & 31;
    const double* D = SHD + g * 1024;       // D[k*32+i] = L[i][k]
    double x[32];
#pragma unroll
    for (int i = 0; i < 32; ++i) {
        double s = (i == j) ? 1.0 : 0.0;
#pragma unroll
        for (int k = 0; k < i; ++k) {
            double lv = D[k * 32 + i];
            s -= (k >= j) ? lv * x[k] : 0.0;
        }
        double inv = 1.0 / D[i * 32 + i];
        x[i] = (i >= j) ? s * inv : 0.0;
    }
#pragma unroll
    for (int i = 0; i < 32; ++i) {
        int gi = 32 * g + i, gj = 32 * g + j;
        TIb[gi * 256 + gj] = x[i];
        TIFb[gi * 256 + gj] = (float)x[i];
    }
}

// ---------------------------------------------------------------------------
// K3c: off-diagonal trinv sweep, COLUMN-BLOCK PARALLEL.
//      grid = (B, 7): block (b, J) computes X_IJ for I = J+1..7 where
//      X_IJ = -TinvII * (sum_{K=J}^{I-1} L_IK @ X_KJ).
// ---------------------------------------------------------------------------
__global__ __launch_bounds__(256) void k_trinv(const double* __restrict__ LT,
                                               double* __restrict__ TI,
                                               float* __restrict__ TIF) {
    __shared__ double XS[8][1024];   // XS[K][kk*32+j] = X[32K+kk][32J+j]; XS[7] = Bsh/Lsh
    int b = blockIdx.x, J = blockIdx.y;      // J in 0..6
    int tid = threadIdx.x, j = tid & 31, ig = tid >> 5;
    const double* LTb = LT + b * 65536;
    double* TIb = TI + b * 65536;
    float* TIFb = TIF + b * 65536;
    double* Bsh = XS[7];                      // scratch: staged L tile / C tile

    // preload X_JJ (diag inverse) into the column cache
    for (int idx = tid; idx < 1024; idx += 256) {
        int kk = idx >> 5, c = idx & 31;
        XS[J][idx] = TIb[(32 * J + kk) * 256 + 32 * J + c];
    }
    __syncthreads();

    for (int I = J + 1; I < 8; ++I) {
        double acc[4] = {0.0, 0.0, 0.0, 0.0};
        for (int K = J; K < I; ++K) {
            // stage L_IK: Lsh[kk*32+i2] = L[32I+i2][32K+kk]  (coalesced in i2)
            for (int idx = tid; idx < 1024; idx += 256) {
                int kk = idx >> 5, i2 = idx & 31;
                Bsh[idx] = LTb[(32 * K + kk) * 256 + 32 * I + i2];
            }
            __syncthreads();
            const double* Xk = XS[K];
            for (int kk = 0; kk < 32; ++kk) {
                double tv = Xk[kk * 32 + j];
#pragma unroll
                for (int r = 0; r < 4; ++r)
                    acc[r] += Bsh[kk * 32 + ig * 4 + r] * tv;
            }
            __syncthreads();   // protect Bsh before next stage / C write
        }
        // C tile -> Bsh
#pragma unroll
        for (int r = 0; r < 4; ++r) Bsh[(ig * 4 + r) * 32 + j] = acc[r];
        __syncthreads();
        // X_IJ = -TinvII @ C
        double c[4] = {0.0, 0.0, 0.0, 0.0};
        for (int k = 0; k < 32; ++k) {
            double bv = Bsh[k * 32 + j];
#pragma unroll
            for (int r = 0; r < 4; ++r)
                c[r] -= TIb[(32 * I + ig * 4 + r) * 256 + 32 * I + k] * bv;
        }
#pragma unroll
        for (int r = 0; r < 4; ++r) {
            int gi = 32 * I + ig * 4 + r, gj = 32 * J + j;
            TIb[gi * 256 + gj] = c[r];
            TIFb[gi * 256 + gj] = (float)c[r];
            if (I < 7) XS[I][(ig * 4 + r) * 32 + j] = c[r];
        }
        __syncthreads();   // Bsh reads done + XS[I] visible before next I
    }
}

// ---------------------------------------------------------------------------
// K4a: Z = Tinv @ RHS  (fp64 tiled GEMM, triangular k-skip)
// ---------------------------------------------------------------------------
__global__ __launch_bounds__(256) void k_gemm_Z(const double* __restrict__ TI,
                                                const double* __restrict__ RHS,
                                                double* __restrict__ Z) {
    __shared__ double As[32][64];
    __shared__ double Bs[64][64];
    int b = blockIdx.x, i0 = blockIdx.y * 32;
    int tid = threadIdx.x, c = tid & 63, rg = tid >> 6;
    const double* TIb = TI + b * 65536;
    const double* Rb = RHS + b * 16384;
    double* Zb = Z + b * 16384;
    double acc[8] = {};
    for (int k0 = 0; k0 <= i0; k0 += 64) {
        for (int idx = tid; idx < 2048; idx += 256) {
            int r = idx >> 6, kk = idx & 63;
            As[r][kk] = TIb[(i0 + r) * 256 + k0 + kk];
        }
        for (int idx = tid; idx < 4096; idx += 256) {
            int kk = idx >> 6, cc = idx & 63;
            Bs[kk][cc] = Rb[(k0 + kk) * 64 + cc];
        }
        __syncthreads();
        for (int kk = 0; kk < 64; ++kk) {
            double bv = Bs[kk][c];
#pragma unroll
            for (int r = 0; r < 8; ++r)
                acc[r] += As[rg * 8 + r][kk] * bv;
        }
        __syncthreads();
    }
#pragma unroll
    for (int r = 0; r < 8; ++r)
        Zb[(i0 + rg * 8 + r) * 64 + c] = acc[r];
}

// ---------------------------------------------------------------------------
// K4b: M = Tinv^T @ Z  (fp64 tiled GEMM, triangular k-skip), M -> RHS buffer
// ---------------------------------------------------------------------------
__global__ __launch_bounds__(256) void k_gemm_M(const double* __restrict__ TI,
                                                const double* __restrict__ Z,
                                                double* __restrict__ M) {
    __shared__ double As[64][32];
    __shared__ double Bs[64][64];
    int b = blockIdx.x, i0 = blockIdx.y * 32;
    int tid = threadIdx.x, c = tid & 63, rg = tid >> 6;
    const double* TIb = TI + b * 65536;
    const double* Zb = Z + b * 16384;
    double* Mb = M + b * 16384;
    double acc[8] = {};
    for (int k0 = (i0 >> 6) << 6; k0 < 256; k0 += 64) {
        for (int idx = tid; idx < 2048; idx += 256) {
            int kk = idx >> 5, ri = idx & 31;
            As[kk][ri] = TIb[(k0 + kk) * 256 + i0 + ri];
        }
        for (int idx = tid; idx < 4096; idx += 256) {
            int kk = idx >> 6, cc = idx & 63;
            Bs[kk][cc] = Zb[(k0 + kk) * 64 + cc];
        }
        __syncthreads();
        for (int kk = 0; kk < 64; ++kk) {
            double bv = Bs[kk][c];
#pragma unroll
            for (int r = 0; r < 8; ++r)
                acc[r] += As[kk][rg * 8 + r] * bv;
        }
        __syncthreads();
    }
#pragma unroll
    for (int r = 0; r < 8; ++r)
        Mb[(i0 + rg * 8 + r) * 64 + c] = acc[r];
}

// ---------------------------------------------------------------------------
// K5: W = PhiQ @ TinvF^T, PSUM[b][I][q] = sum_{i in I-tile} W[q][i]^2 (fp32)
// ---------------------------------------------------------------------------
__global__ __launch_bounds__(256) void k_spread_gemm(const float* __restrict__ PHIQ,
                                                     const float* __restrict__ TIF,
                                                     float* __restrict__ PSUM) {
    __shared__ float Qs[64][65];   // [q][k]
    __shared__ float Ts[64][65];   // [k][i]
    int b = blockIdx.x, q0 = blockIdx.y * 64, I = blockIdx.z, i0 = I * 64;
    int tid = threadIdx.x, tx = tid & 15, ty = tid >> 4;
    const float* Qb = PHIQ + b * (NQ * DIN) + q0 * DIN;
    const float* Tb = TIF + b * 65536;
    float acc[4][4];
#pragma unroll
    for (int r = 0; r < 4; ++r)
#pragma unroll
        for (int s = 0; s < 4; ++s) acc[r][s] = 0.0f;
    for (int k0 = 0; k0 <= i0; k0 += 64) {
        for (int idx = tid; idx < 4096; idx += 256) {
            int r = idx >> 6, c = idx & 63;
            Qs[r][c] = Qb[r * 256 + k0 + c];
            Ts[c][r] = Tb[(i0 + r) * 256 + k0 + c];
        }
        __syncthreads();
        for (int kk = 0; kk < 64; ++kk) {
            float a0 = Qs[4 * ty + 0][kk], a1 = Qs[4 * ty + 1][kk];
            float a2 = Qs[4 * ty + 2][kk], a3 = Qs[4 * ty + 3][kk];
            float b0 = Ts[kk][4 * tx + 0], b1 = Ts[kk][4 * tx + 1];
            float b2 = Ts[kk][4 * tx + 2], b3 = Ts[kk][4 * tx + 3];
            acc[0][0] += a0 * b0; acc[0][1] += a0 * b1; acc[0][2] += a0 * b2; acc[0][3] += a0 * b3;
            acc[1][0] += a1 * b0; acc[1][1] += a1 * b1; acc[1][2] += a1 * b2; acc[1][3] += a1 * b3;
            acc[2][0] += a2 * b0; acc[2][1] += a2 * b1; acc[2][2] += a2 * b2; acc[2][3] += a2 * b3;
            acc[3][0] += a3 * b0; acc[3][1] += a3 * b1; acc[3][2] += a3 * b2; acc[3][3] += a3 * b3;
        }
        __syncthreads();
    }
#pragma unroll
    for (int r = 0; r < 4; ++r) {
        float p = acc[r][0] * acc[r][0] + acc[r][1] * acc[r][1]
                + acc[r][2] * acc[r][2] + acc[r][3] * acc[r][3];
        p += __shfl_down(p, 8, 16);
        p += __shfl_down(p, 4, 16);
        p += __shfl_down(p, 2, 16);
        p += __shfl_down(p, 1, 16);
        if (tx == 0) PSUM[(size_t)(b * 4 + I) * 512 + q0 + 4 * ty + r] = p;
    }
}

// ---------------------------------------------------------------------------
// K6: mu = Phi_q @ m (fp32), FUSED epilogue: spread combine -> SPREAD,
//     nll partial (resid^2, logs) -> one fp64 atomicAdd per block.
// ---------------------------------------------------------------------------
__global__ __launch_bounds__(256) void k_mu_nll(const float* __restrict__ PHIQ,
                                                const double* __restrict__ M,
                                                const float* __restrict__ YQ,
                                                const float* __restrict__ PSUM,
                                                const float* __restrict__ SE,
                                                float* __restrict__ SPREAD,
                                                double* __restrict__ NLLACC,
                                                float* __restrict__ MU) {
    __shared__ float Qs[64][65];
    __shared__ float Ms[64][64];
    __shared__ double nred[64];
    int b = blockIdx.x, q0 = blockIdx.y * 64, tid = threadIdx.x;
    int tx = tid & 15, ty = tid >> 4;
    const float* Qb = PHIQ + b * (NQ * DIN) + q0 * DIN;
    const double* Mb = M + b * 16384;
    float acc[4][4];
#pragma unroll
    for (int r = 0; r < 4; ++r)
#pragma unroll
        for (int s = 0; s < 4; ++s) acc[r][s] = 0.0f;
    for (int c0 = 0; c0 < 256; c0 += 64) {
        for (int idx = tid; idx < 4096; idx += 256) {
            int r = idx >> 6, c = idx & 63;
            Qs[r][c] = Qb[r * 256 + c0 + c];
            Ms[r][c] = (float)Mb[(c0 + r) * 64 + c];
        }
        __syncthreads();
        for (int kk = 0; kk < 64; ++kk) {
            float a0 = Qs[4 * ty + 0][kk], a1 = Qs[4 * ty + 1][kk];
            float a2 = Qs[4 * ty + 2][kk], a3 = Qs[4 * ty + 3][kk];
            float b0 = Ms[kk][4 * tx + 0], b1 = Ms[kk][4 * tx + 1];
            float b2 = Ms[kk][4 * tx + 2], b3 = Ms[kk][4 * tx + 3];
            acc[0][0] += a0 * b0; acc[0][1] += a0 * b1; acc[0][2] += a0 * b2; acc[0][3] += a0 * b3;
            acc[1][0] += a1 * b0; acc[1][1] += a1 * b1; acc[1][2] += a1 * b2; acc[1][3] += a1 * b3;
            acc[2][0] += a2 * b0; acc[2][1] += a2 * b1; acc[2][2] += a2 * b2; acc[2][3] += a2 * b3;
            acc[3][0] += a3 * b0; acc[3][1] += a3 * b1; acc[3][2] += a3 * b2; acc[3][3] += a3 * b3;
        }
        __syncthreads();
    }
    float se = SE[0];
#pragma unroll
    for (int r = 0; r < 4; ++r) {
        int q = q0 + 4 * ty + r;
        float4 v = make_float4(acc[r][0], acc[r][1], acc[r][2], acc[r][3]);
        *(float4*)&MU[(b * NQ + q) * 64 + 4 * tx] = v;
        // nll partial for this row
        float4 y = *(const float4*)&YQ[(size_t)(b * NQ + q) * 64 + 4 * tx];
        float dx = y.x - v.x, dy = y.y - v.y, dz = y.z - v.z, dw = y.w - v.w;
        float qs = dx * dx + dy * dy + dz * dz + dw * dw;
        qs += __shfl_down(qs, 8, 16);
        qs += __shfl_down(qs, 4, 16);
        qs += __shfl_down(qs, 2, 16);
        qs += __shfl_down(qs, 1, 16);
        if (tx == 0) {
            float sp = 1.0f + PSUM[(size_t)(b * 4 + 0) * 512 + q]
                            + PSUM[(size_t)(b * 4 + 1) * 512 + q]
                            + PSUM[(size_t)(b * 4 + 2) * 512 + q]
                            + PSUM[(size_t)(b * 4 + 3) * 512 + q];
            SPREAD[b * 512 + q] = sp;
            float val = 64.0f * (logf(sp) + logf(se)) + qs / (sp * se);
            nred[ty * 4 + r] = (double)val;
        }
    }
    __syncthreads();
    for (int s = 32; s > 0; s >>= 1) {
        if (tid < s) nred[tid] += nred[tid + s];
        __syncthreads();
    }
    if (tid == 0) atomicAdd(NLLACC, nred[0] * (1.0 / 65536.0));
}

// ---------------------------------------------------------------------------
// K6b: write nll scalar
// ---------------------------------------------------------------------------
__global__ void k_nll_final(const double* __restrict__ NLLACC,
                            float* __restrict__ out) {
    if (threadIdx.x == 0) out[NLL_IDX] = (float)NLLACC[0];
}

// ---------------------------------------------------------------------------
// K7 (runs LAST): stream sig; fully overwrites scratch inside d_out sig region.
// ---------------------------------------------------------------------------
__global__ __launch_bounds__(256) void k_sig(const float* __restrict__ SPREAD,
                                             const float* __restrict__ SE,
                                             float* __restrict__ out) {
    __shared__ float sv_s;
    int bq = blockIdx.x, tid = threadIdx.x;
    if (tid == 0) sv_s = SPREAD[bq] * SE[0];
    __syncthreads();
    float sv = sv_s;
    float* base = out + (size_t)MU_SIZE + (size_t)bq * 4096;
    int i = tid >> 2;
    int jb = (tid & 3) << 4;
    int d = i - jb;
    float vals[16];
#pragma unroll
    for (int t = 0; t < 16; ++t) vals[t] = (t == d) ? sv : 0.0f;
    float4* p = (float4*)(base + tid * 16);
    p[0] = make_float4(vals[0], vals[1], vals[2], vals[3]);
    p[1] = make_float4(vals[4], vals[5], vals[6], vals[7]);
    p[2] = make_float4(vals[8], vals[9], vals[10], vals[11]);
    p[3] = make_float4(vals[12], vals[13], vals[14], vals[15]);
}

// ---------------------------------------------------------------------------
extern "C" void kernel_launch(void* const* d_in, const int* in_sizes, int n_in,
                              void* d_out, int out_size, void* d_ws, size_t ws_size,
                              hipStream_t stream) {
    const float* PHI_S = (const float*)d_in[0];
    const float* Y_S   = (const float*)d_in[1];
    const float* PHI_Q = (const float*)d_in[2];
    const float* Y_Q   = (const float*)d_in[3];
    const float* MP    = (const float*)d_in[4];
    const float* AP    = (const float*)d_in[5];
    const float* SE    = (const float*)d_in[6];
    float* out = (float*)d_out;

    // Big scratch inside sig region of d_out (dead before k_sig runs last).
    double* scratch = (double*)(out + MU_SIZE);
    double* G    = scratch;                    // 8,388,608 dbl (64 MB)
    double* LT   = G + 8388608;                // 8,388,608 dbl
    double* RHS  = LT + 8388608;               // 2,097,152 dbl (-> becomes M)
    double* Z    = RHS + 2097152;              // 2,097,152 dbl
    double* TI   = Z + 2097152;                // 8,388,608 dbl
    double* Spd  = TI + 8388608;               // 65,536 dbl
    double* MPN  = Spd + 65536;                // 16,384 dbl
    float*  TIF  = (float*)(MPN + 16384);      // 8,388,608 f32 (32 MB)
    float*  PSUM = TIF + 8388608;              // 262,144 f32 (1 MB)
    // Small persistent scratch (survives until k_sig) in d_ws (proven 258 KB).
    float*  SPREAD = (float*)d_ws;                        // 65,536 f32
    double* NLLACC = (double*)((char*)d_ws + 65536 * 4);  // 1 dbl

    k_prior_sp   <<<256, 256, 0, stream>>>(AP, Spd, NLLACC);
    k_prior_mpn  <<<256, 64, 0, stream>>>(Spd, MP, MPN);
    k_build_G    <<<dim3(B_T, 10), 256, 0, stream>>>(PHI_S, Spd, G);
    k_build_rhs  <<<dim3(B_T, 4), 256, 0, stream>>>(PHI_S, Y_S, MPN, RHS);
    k_chol       <<<B_T, 512, 0, stream>>>(G, LT);
    k_diaginv    <<<B_T, 256, 0, stream>>>(LT, TI, TIF);
    k_trinv      <<<dim3(B_T, 7), 256, 0, stream>>>(LT, TI, TIF);
    k_gemm_Z     <<<dim3(B_T, 8), 256, 0, stream>>>(TI, RHS, Z);
    k_gemm_M     <<<dim3(B_T, 8), 256, 0, stream>>>(TI, Z, RHS);
    k_spread_gemm<<<dim3(B_T, 8, 4), 256, 0, stream>>>(PHI_Q, TIF, PSUM);
    k_mu_nll     <<<dim3(B_T, 8), 256, 0, stream>>>(PHI_Q, RHS, Y_Q, PSUM, SE,
                                                    SPREAD, NLLACC, out);
    k_nll_final  <<<1, 64, 0, stream>>>(NLLACC, out);
    k_sig        <<<65536, 256, 0, stream>>>(SPREAD, SE, out);   // LAST
}

// Round 4
// 2089.662 us; speedup vs baseline: 1.2950x; 1.1045x over previous
//
#include <hip/hip_runtime.h>
#include <math.h>

#define B_T   128
#define NS    128
#define NQ    512
#define DIN   256
#define DOUT  64

#define MU_SIZE  (B_T*NQ*DOUT)            // 4,194,304 floats
#define SIG_SIZE (B_T*NQ*DOUT*DOUT)       // 268,435,456 floats
#define NLL_IDX  (MU_SIZE + SIG_SIZE)     // 272,629,760

// ---------------------------------------------------------------------------
// K0a: Sp = A @ A^T  (fp64 accumulate); also zeroes the NLL accumulator.
// ---------------------------------------------------------------------------
__global__ __launch_bounds__(256) void k_prior_sp(const float* __restrict__ A,
                                                  double* __restrict__ Sp,
                                                  double* __restrict__ NLLACC) {
    __shared__ float Ai[16][260];
    __shared__ float Aj[16][260];
    int bi = blockIdx.x;
    int i0 = (bi >> 4) << 4;
    int j0 = (bi & 15) << 4;
    int tid = threadIdx.x;
    if (bi == 0 && tid == 0) NLLACC[0] = 0.0;
    for (int idx = tid; idx < 16 * 256; idx += 256) {
        int r = idx >> 8, c = idx & 255;
        Ai[r][c] = A[(i0 + r) * 256 + c];
        Aj[r][c] = A[(j0 + r) * 256 + c];
    }
    __syncthreads();
    int r = tid >> 4, c = tid & 15;
    double acc = 0.0;
    for (int k = 0; k < 256; ++k)
        acc += (double)Ai[r][k] * (double)Aj[c][k];
    Sp[(i0 + r) * 256 + (j0 + c)] = acc;
}

// ---------------------------------------------------------------------------
// K0b: MPN = Sp @ m_prior
// ---------------------------------------------------------------------------
__global__ __launch_bounds__(64) void k_prior_mpn(const double* __restrict__ Sp,
                                                  const float* __restrict__ MP,
                                                  double* __restrict__ MPN) {
    int i = blockIdx.x, k = threadIdx.x;
    double acc = 0.0;
    for (int t = 0; t < 256; ++t)
        acc += Sp[i * 256 + t] * (double)MP[t * 64 + k];
    MPN[i * 64 + k] = acc;
}

// ---------------------------------------------------------------------------
// K1: G_b = Phi_s^T Phi_s + Sp   (lower-triangle 64x64 tiles only, fp64)
// ---------------------------------------------------------------------------
__global__ __launch_bounds__(256) void k_build_G(const float* __restrict__ PHI,
                                                 const double* __restrict__ Sp,
                                                 double* __restrict__ G) {
    __shared__ float As[128][64];
    __shared__ float Bs[128][64];
    int b = blockIdx.x;
    int by = blockIdx.y;
    int ti = 0;
    while (((ti + 1) * (ti + 2)) / 2 <= by) ti++;
    int tj = by - (ti * (ti + 1)) / 2;
    int i0 = ti * 64, j0 = tj * 64;
    int tid = threadIdx.x;
    const float* Pb = PHI + b * (NS * DIN);
    for (int idx = tid; idx < 128 * 64; idx += 256) {
        int n = idx >> 6, c = idx & 63;
        As[n][c] = Pb[n * 256 + i0 + c];
        Bs[n][c] = Pb[n * 256 + j0 + c];
    }
    __syncthreads();
    int tx = tid & 15, ty = tid >> 4;
    double acc[4][4];
#pragma unroll
    for (int r = 0; r < 4; ++r)
#pragma unroll
        for (int s = 0; s < 4; ++s) acc[r][s] = 0.0;
    for (int n = 0; n < 128; ++n) {
        float a0 = As[n][4 * ty + 0], a1 = As[n][4 * ty + 1];
        float a2 = As[n][4 * ty + 2], a3 = As[n][4 * ty + 3];
        float b0 = Bs[n][4 * tx + 0], b1 = Bs[n][4 * tx + 1];
        float b2 = Bs[n][4 * tx + 2], b3 = Bs[n][4 * tx + 3];
        acc[0][0] += (double)a0 * b0; acc[0][1] += (double)a0 * b1;
        acc[0][2] += (double)a0 * b2; acc[0][3] += (double)a0 * b3;
        acc[1][0] += (double)a1 * b0; acc[1][1] += (double)a1 * b1;
        acc[1][2] += (double)a1 * b2; acc[1][3] += (double)a1 * b3;
        acc[2][0] += (double)a2 * b0; acc[2][1] += (double)a2 * b1;
        acc[2][2] += (double)a2 * b2; acc[2][3] += (double)a2 * b3;
        acc[3][0] += (double)a3 * b0; acc[3][1] += (double)a3 * b1;
        acc[3][2] += (double)a3 * b2; acc[3][3] += (double)a3 * b3;
    }
    double* Gb = G + b * 65536;
#pragma unroll
    for (int r = 0; r < 4; ++r) {
        int i = i0 + 4 * ty + r;
#pragma unroll
        for (int s = 0; s < 4; ++s) {
            int j = j0 + 4 * tx + s;
            Gb[i * 256 + j] = acc[r][s] + Sp[i * 256 + j];
        }
    }
}

// ---------------------------------------------------------------------------
// K2: RHS_b = Phi_s^T Y_s + MPN  (fp64)
// ---------------------------------------------------------------------------
__global__ __launch_bounds__(256) void k_build_rhs(const float* __restrict__ PHI,
                                                   const float* __restrict__ Y,
                                                   const double* __restrict__ MPN,
                                                   double* __restrict__ RHS) {
    __shared__ float As[128][64];
    __shared__ float Ys[128][64];
    int b = blockIdx.x, i0 = blockIdx.y * 64, tid = threadIdx.x;
    const float* Pb = PHI + b * (NS * DIN);
    const float* Yb = Y + b * (NS * DOUT);
    for (int idx = tid; idx < 128 * 64; idx += 256) {
        int n = idx >> 6, c = idx & 63;
        As[n][c] = Pb[n * 256 + i0 + c];
        Ys[n][c] = Yb[n * 64 + c];
    }
    __syncthreads();
    int tx = tid & 15, ty = tid >> 4;
    double acc[4][4];
#pragma unroll
    for (int r = 0; r < 4; ++r)
#pragma unroll
        for (int s = 0; s < 4; ++s) acc[r][s] = 0.0;
    for (int n = 0; n < 128; ++n) {
        float a0 = As[n][4 * ty + 0], a1 = As[n][4 * ty + 1];
        float a2 = As[n][4 * ty + 2], a3 = As[n][4 * ty + 3];
        float y0 = Ys[n][4 * tx + 0], y1 = Ys[n][4 * tx + 1];
        float y2 = Ys[n][4 * tx + 2], y3 = Ys[n][4 * tx + 3];
        acc[0][0] += (double)a0 * y0; acc[0][1] += (double)a0 * y1;
        acc[0][2] += (double)a0 * y2; acc[0][3] += (double)a0 * y3;
        acc[1][0] += (double)a1 * y0; acc[1][1] += (double)a1 * y1;
        acc[1][2] += (double)a1 * y2; acc[1][3] += (double)a1 * y3;
        acc[2][0] += (double)a2 * y0; acc[2][1] += (double)a2 * y1;
        acc[2][2] += (double)a2 * y2; acc[2][3] += (double)a2 * y3;
        acc[3][0] += (double)a3 * y0; acc[3][1] += (double)a3 * y1;
        acc[3][2] += (double)a3 * y2; acc[3][3] += (double)a3 * y3;
    }
    double* Rb = RHS + b * 16384;
#pragma unroll
    for (int r = 0; r < 4; ++r) {
        int i = i0 + 4 * ty + r;
#pragma unroll
        for (int s = 0; s < 4; ++s) {
            int kc = 4 * tx + s;
            Rb[i * 64 + kc] = acc[r][s] + MPN[i * 64 + kc];
        }
    }
}

// ---------------------------------------------------------------------------
// K3a: POTRF64 — factor 64x64 diag block kb of G in LDS; write L11 -> LT and
//      L11^{-1} -> LI (transposed layout LIT[p][c] = Linv[c][p] for coalesced
//      consumption by k_trsm64). One block per task; zero global RMW.
//      Components (shfl diag16, row-solve16, diaginv32) are HW-verified.
// ---------------------------------------------------------------------------
__global__ __launch_bounds__(256) void k_potrf64(const double* __restrict__ G,
                                                 double* __restrict__ LT,
                                                 double* __restrict__ LI,
                                                 int kb) {
    __shared__ double D[64][65];      // 33.3 KB working block
    __shared__ double T[64][33];      // T11 rows 0-31, T22 rows 32-63 (16.9 KB)
    __shared__ double C[32][33];      // L21 @ T11 scratch (8.4 KB)
    __shared__ double L11s[16 * 17];
    __shared__ double DINVs[16];
    int b = blockIdx.x, tid = threadIdx.x;
    int o = kb * 64;
    const double* Gb = G + b * 65536;
    double* LTb = LT + b * 65536;
    double* LIb = LI + b * 16384 + kb * 4096;
    // stage diagonal block (coalesced)
    for (int idx = tid; idx < 4096; idx += 256) {
        int r = idx >> 6, c = idx & 63;
        D[r][c] = Gb[(o + r) * 256 + o + c];
    }
    __syncthreads();
    // ---- factor in LDS: 4 sub-panels of 16 ----
    for (int p0 = 0; p0 < 64; p0 += 16) {
        // wave 0: factor 16x16 diag via shuffles (proven)
        if (tid < 64) {
            int lane = tid;
            double a[16];
            if (lane < 16) {
#pragma unroll
                for (int p = 0; p < 16; ++p) a[p] = D[p0 + lane][p0 + p];
            }
#pragma unroll
            for (int p = 0; p < 16; ++p) {
                double dp = __shfl(a[p], p);
                double d = sqrt(fmax(dp, 1e-300));
                double inv = 1.0 / d;
                if (lane == p) { a[p] = d; DINVs[p] = inv; }
                else if (lane > p) a[p] *= inv;
#pragma unroll
                for (int p2 = p + 1; p2 < 16; ++p2) {
                    double cc = __shfl(a[p], p2);
                    if (lane > p) a[p2] -= a[p] * cc;
                }
            }
            if (lane < 16) {
#pragma unroll
                for (int p = 0; p < 16; ++p) {
                    if (p <= lane) {
                        L11s[lane * 17 + p] = a[p];
                        D[p0 + lane][p0 + p] = a[p];
                    }
                }
            }
        }
        __syncthreads();
        // row-solve rows p0+16..63 (proven pattern)
        int nsolve = 48 - p0;
        if (tid < nsolve) {
            int rr = p0 + 16 + tid;
            double x[16];
#pragma unroll
            for (int p = 0; p < 16; ++p) {
                double s = D[rr][p0 + p];
#pragma unroll
                for (int p2 = 0; p2 < 16; ++p2) {
                    if (p2 < p) s -= L11s[p * 17 + p2] * x[p2];
                }
                x[p] = s * DINVs[p];
                D[rr][p0 + p] = x[p];
            }
        }
        __syncthreads();
        // trailing update within the 64x64 block, all in LDS
        int rem = nsolve;
        for (int idx = tid; idx < rem * rem; idx += 256) {
            int i2 = idx / rem, j2 = idx - i2 * rem;
            if (j2 <= i2) {
                int i = p0 + 16 + i2, j = p0 + 16 + j2;
                double s = 0.0;
#pragma unroll
                for (int p = 0; p < 16; ++p) s += D[i][p0 + p] * D[j][p0 + p];
                D[i][j] -= s;
            }
        }
        __syncthreads();
    }
    // ---- write L11 to LT (coalesced along r) ----
    for (int idx = tid; idx < 4096; idx += 256) {
        int c = idx >> 6, r = idx & 63;
        if (r >= c) LTb[(o + c) * 256 + (o + r)] = D[r][c];
    }
    // ---- invert 32x32 diag sub-blocks (proven diaginv pattern) ----
    if (tid < 64) {
        int g = tid >> 5, j = tid & 31;
        int off = g * 32;
        double x[32];
#pragma unroll
        for (int i = 0; i < 32; ++i) {
            double s = (i == j) ? 1.0 : 0.0;
#pragma unroll
            for (int k = 0; k < i; ++k) {
                double lv = D[off + i][off + k];
                s -= (k >= j) ? lv * x[k] : 0.0;
            }
            double inv = 1.0 / D[off + i][off + i];
            x[i] = (i >= j) ? s * inv : 0.0;
        }
#pragma unroll
        for (int i = 0; i < 32; ++i) T[off + i][j] = x[i];
    }
    __syncthreads();
    // ---- C = L21 @ T11 ----
    for (int idx = tid; idx < 1024; idx += 256) {
        int r = idx >> 5, c = idx & 31;
        double s = 0.0;
#pragma unroll
        for (int p = 0; p < 32; ++p) s += D[32 + r][p] * T[p][c];
        C[r][c] = s;
    }
    __syncthreads();
    // ---- X21 = -T22 @ C, store into D[32+r][c] (L21 no longer needed) ----
    for (int idx = tid; idx < 1024; idx += 256) {
        int r = idx >> 5, c = idx & 31;
        double s = 0.0;
#pragma unroll
        for (int p = 0; p < 32; ++p) s += T[32 + r][p] * C[p][c];
        D[32 + r][c] = -s;
    }
    __syncthreads();
    // ---- write LI transposed: LIT[p][c] = Linv[row=c][col=p], coalesced ----
    for (int idx = tid; idx < 4096; idx += 256) {
        int p = idx >> 6, c = idx & 63;
        double v;
        if (c < 32) v = (p < 32) ? T[c][p] : 0.0;
        else        v = (p < 32) ? D[c][p] : T[c][p - 32];
        LIb[p * 64 + c] = v;
    }
}

// ---------------------------------------------------------------------------
// K3a': TRSM64 — L21 tile = G21 tile @ L11^{-T}. Pure 64x64x64 fp64 GEMM.
//       grid (B, 3-kb); row-tile i = kb+1+blockIdx.y.
// ---------------------------------------------------------------------------
__global__ __launch_bounds__(256) void k_trsm64(const double* __restrict__ G,
                                                const double* __restrict__ LI,
                                                double* __restrict__ LT,
                                                int kb) {
    __shared__ double Gs[64][65];   // G21 [r][p]
    __shared__ double Ls[64][65];   // LIT [p][c] = Linv[c][p]
    int b = blockIdx.x;
    int i0 = (kb + 1 + blockIdx.y) * 64;
    int o = kb * 64;
    int tid = threadIdx.x;
    const double* Gb = G + b * 65536;
    const double* LIb = LI + b * 16384 + kb * 4096;
    double* LTb = LT + b * 65536;
    for (int idx = tid; idx < 4096; idx += 256) {
        int r = idx >> 6, c = idx & 63;
        Gs[r][c] = Gb[(i0 + r) * 256 + o + c];
        Ls[r][c] = LIb[idx];
    }
    __syncthreads();
    int tx = tid & 15, ty = tid >> 4;
    double acc[4][4];
#pragma unroll
    for (int r = 0; r < 4; ++r)
#pragma unroll
        for (int s = 0; s < 4; ++s) acc[r][s] = 0.0;
    for (int kk = 0; kk < 64; ++kk) {
        double a0 = Gs[4 * ty + 0][kk], a1 = Gs[4 * ty + 1][kk];
        double a2 = Gs[4 * ty + 2][kk], a3 = Gs[4 * ty + 3][kk];
        double b0 = Ls[kk][4 * tx + 0], b1 = Ls[kk][4 * tx + 1];
        double b2 = Ls[kk][4 * tx + 2], b3 = Ls[kk][4 * tx + 3];
        acc[0][0] += a0 * b0; acc[0][1] += a0 * b1; acc[0][2] += a0 * b2; acc[0][3] += a0 * b3;
        acc[1][0] += a1 * b0; acc[1][1] += a1 * b1; acc[1][2] += a1 * b2; acc[1][3] += a1 * b3;
        acc[2][0] += a2 * b0; acc[2][1] += a2 * b1; acc[2][2] += a2 * b2; acc[2][3] += a2 * b3;
        acc[3][0] += a3 * b0; acc[3][1] += a3 * b1; acc[3][2] += a3 * b2; acc[3][3] += a3 * b3;
    }
#pragma unroll
    for (int r = 0; r < 4; ++r)
#pragma unroll
        for (int s = 0; s < 4; ++s)
            LTb[(o + 4 * tx + s) * 256 + i0 + 4 * ty + r] = acc[r][s];
}

// ---------------------------------------------------------------------------
// K3a'': SYRK64 — G[i,j] tile -= L21[i] @ L21[j]^T for remaining tile pairs.
//        grid (B, npairs). Each G element RMW'd exactly once per kb.
// ---------------------------------------------------------------------------
__global__ __launch_bounds__(256) void k_syrk64(const double* __restrict__ LT,
                                                double* __restrict__ G,
                                                int kb) {
    __shared__ double LiT[64][65];  // [p][r] = L21[i-tile][r][p]
    __shared__ double LjT[64][65];  // [p][c]
    int b = blockIdx.x, py = blockIdx.y;
    int ti = 0;
    while (((ti + 1) * (ti + 2)) / 2 <= py) ti++;
    int tj = py - (ti * (ti + 1)) / 2;
    int i0 = (kb + 1 + ti) * 64, j0 = (kb + 1 + tj) * 64;
    int o = kb * 64;
    int tid = threadIdx.x;
    const double* LTb = LT + b * 65536;
    double* Gb = G + b * 65536;
    for (int idx = tid; idx < 4096; idx += 256) {
        int p = idx >> 6, r = idx & 63;
        LiT[p][r] = LTb[(o + p) * 256 + i0 + r];
        LjT[p][r] = LTb[(o + p) * 256 + j0 + r];
    }
    __syncthreads();
    int tx = tid & 15, ty = tid >> 4;
    double acc[4][4];
#pragma unroll
    for (int r = 0; r < 4; ++r)
#pragma unroll
        for (int s = 0; s < 4; ++s) acc[r][s] = 0.0;
    for (int kk = 0; kk < 64; ++kk) {
        double a0 = LiT[kk][4 * ty + 0], a1 = LiT[kk][4 * ty + 1];
        double a2 = LiT[kk][4 * ty + 2], a3 = LiT[kk][4 * ty + 3];
        double b0 = LjT[kk][4 * tx + 0], b1 = LjT[kk][4 * tx + 1];
        double b2 = LjT[kk][4 * tx + 2], b3 = LjT[kk][4 * tx + 3];
        acc[0][0] += a0 * b0; acc[0][1] += a0 * b1; acc[0][2] += a0 * b2; acc[0][3] += a0 * b3;
        acc[1][0] += a1 * b0; acc[1][1] += a1 * b1; acc[1][2] += a1 * b2; acc[1][3] += a1 * b3;
        acc[2][0] += a2 * b0; acc[2][1] += a2 * b1; acc[2][2] += a2 * b2; acc[2][3] += a2 * b3;
        acc[3][0] += a3 * b0; acc[3][1] += a3 * b1; acc[3][2] += a3 * b2; acc[3][3] += a3 * b3;
    }
#pragma unroll
    for (int r = 0; r < 4; ++r) {
        int gi = i0 + 4 * ty + r;
#pragma unroll
        for (int s = 0; s < 4; ++s) {
            int gj = j0 + 4 * tx + s;
            Gb[gi * 256 + gj] -= acc[r][s];
        }
    }
}

// ---------------------------------------------------------------------------
// K3b: zero upper triangle of TI/TIF; invert the 8 diagonal 32x32 blocks of L.
//      One block per task.
// ---------------------------------------------------------------------------
__global__ __launch_bounds__(256) void k_diaginv(const double* __restrict__ LT,
                                                 double* __restrict__ TI,
                                                 float* __restrict__ TIF) {
    __shared__ double SHD[8192];   // 8 diag blocks: SHD[g*1024 + k*32 + i] = L[32g+i][32g+k]
    int b = blockIdx.x, tid = threadIdx.x;
    const double* LTb = LT + b * 65536;
    double* TIb = TI + b * 65536;
    float* TIFb = TIF + b * 65536;
    for (int idx = tid; idx < 65536; idx += 256) {
        int i = idx >> 8, k = idx & 255;
        if (k > i) { TIb[idx] = 0.0; TIFb[idx] = 0.0f; }
    }
    for (int idx = tid; idx < 8192; idx += 256) {
        int g = idx >> 10, rem = idx & 1023, k = rem >> 5, i = rem & 31;
        SHD[idx] = LTb[(32 * g + k) * 256 + 32 * g + i];
    }
    __syncthreads();
    int g = tid >> 5, j = tid & 31;
    const double* D = SHD + g * 1024;       // D[k*32+i] = L[i][k]
    double x[32];
#pragma unroll
    for (int i = 0; i < 32; ++i) {
        double s = (i == j) ? 1.0 : 0.0;
#pragma unroll
        for (int k = 0; k < i; ++k) {
            double lv = D[k * 32 + i];
            s -= (k >= j) ? lv * x[k] : 0.0;
        }
        double inv = 1.0 / D[i * 32 + i];
        x[i] = (i >= j) ? s * inv : 0.0;
    }
#pragma unroll
    for (int i = 0; i < 32; ++i) {
        int gi = 32 * g + i, gj = 32 * g + j;
        TIb[gi * 256 + gj] = x[i];
        TIFb[gi * 256 + gj] = (float)x[i];
    }
}

// ---------------------------------------------------------------------------
// K3c: off-diagonal trinv sweep, COLUMN-BLOCK PARALLEL.
//      grid = (B, 7): block (b, J) computes X_IJ for I = J+1..7 where
//      X_IJ = -TinvII * (sum_{K=J}^{I-1} L_IK @ X_KJ).
// ---------------------------------------------------------------------------
__global__ __launch_bounds__(256) void k_trinv(const double* __restrict__ LT,
                                               double* __restrict__ TI,
                                               float* __restrict__ TIF) {
    __shared__ double XS[8][1024];   // XS[K][kk*32+j] = X[32K+kk][32J+j]; XS[7] = Bsh/Lsh
    int b = blockIdx.x, J = blockIdx.y;      // J in 0..6
    int tid = threadIdx.x, j = tid & 31, ig = tid >> 5;
    const double* LTb = LT + b * 65536;
    double* TIb = TI + b * 65536;
    float* TIFb = TIF + b * 65536;
    double* Bsh = XS[7];                      // scratch: staged L tile / C tile

    // preload X_JJ (diag inverse) into the column cache
    for (int idx = tid; idx < 1024; idx += 256) {
        int kk = idx >> 5, c = idx & 31;
        XS[J][idx] = TIb[(32 * J + kk) * 256 + 32 * J + c];
    }
    __syncthreads();

    for (int I = J + 1; I < 8; ++I) {
        double acc[4] = {0.0, 0.0, 0.0, 0.0};
        for (int K = J; K < I; ++K) {
            // stage L_IK: Lsh[kk*32+i2] = L[32I+i2][32K+kk]  (coalesced in i2)
            for (int idx = tid; idx < 1024; idx += 256) {
                int kk = idx >> 5, i2 = idx & 31;
                Bsh[idx] = LTb[(32 * K + kk) * 256 + 32 * I + i2];
            }
            __syncthreads();
            const double* Xk = XS[K];
            for (int kk = 0; kk < 32; ++kk) {
                double tv = Xk[kk * 32 + j];
#pragma unroll
                for (int r = 0; r < 4; ++r)
                    acc[r] += Bsh[kk * 32 + ig * 4 + r] * tv;
            }
            __syncthreads();   // protect Bsh before next stage / C write
        }
        // C tile -> Bsh
#pragma unroll
        for (int r = 0; r < 4; ++r) Bsh[(ig * 4 + r) * 32 + j] = acc[r];
        __syncthreads();
        // X_IJ = -TinvII @ C
        double c[4] = {0.0, 0.0, 0.0, 0.0};
        for (int k = 0; k < 32; ++k) {
            double bv = Bsh[k * 32 + j];
#pragma unroll
            for (int r = 0; r < 4; ++r)
                c[r] -= TIb[(32 * I + ig * 4 + r) * 256 + 32 * I + k] * bv;
        }
#pragma unroll
        for (int r = 0; r < 4; ++r) {
            int gi = 32 * I + ig * 4 + r, gj = 32 * J + j;
            TIb[gi * 256 + gj] = c[r];
            TIFb[gi * 256 + gj] = (float)c[r];
            if (I < 7) XS[I][(ig * 4 + r) * 32 + j] = c[r];
        }
        __syncthreads();   // Bsh reads done + XS[I] visible before next I
    }
}

// ---------------------------------------------------------------------------
// K4a: Z = Tinv @ RHS  (fp64 tiled GEMM, triangular k-skip)
// ---------------------------------------------------------------------------
__global__ __launch_bounds__(256) void k_gemm_Z(const double* __restrict__ TI,
                                                const double* __restrict__ RHS,
                                                double* __restrict__ Z) {
    __shared__ double As[32][64];
    __shared__ double Bs[64][64];
    int b = blockIdx.x, i0 = blockIdx.y * 32;
    int tid = threadIdx.x, c = tid & 63, rg = tid >> 6;
    const double* TIb = TI + b * 65536;
    const double* Rb = RHS + b * 16384;
    double* Zb = Z + b * 16384;
    double acc[8] = {};
    for (int k0 = 0; k0 <= i0; k0 += 64) {
        for (int idx = tid; idx < 2048; idx += 256) {
            int r = idx >> 6, kk = idx & 63;
            As[r][kk] = TIb[(i0 + r) * 256 + k0 + kk];
        }
        for (int idx = tid; idx < 4096; idx += 256) {
            int kk = idx >> 6, cc = idx & 63;
            Bs[kk][cc] = Rb[(k0 + kk) * 64 + cc];
        }
        __syncthreads();
        for (int kk = 0; kk < 64; ++kk) {
            double bv = Bs[kk][c];
#pragma unroll
            for (int r = 0; r < 8; ++r)
                acc[r] += As[rg * 8 + r][kk] * bv;
        }
        __syncthreads();
    }
#pragma unroll
    for (int r = 0; r < 8; ++r)
        Zb[(i0 + rg * 8 + r) * 64 + c] = acc[r];
}

// ---------------------------------------------------------------------------
// K4b: M = Tinv^T @ Z  (fp64 tiled GEMM, triangular k-skip), M -> RHS buffer
// ---------------------------------------------------------------------------
__global__ __launch_bounds__(256) void k_gemm_M(const double* __restrict__ TI,
                                                const double* __restrict__ Z,
                                                double* __restrict__ M) {
    __shared__ double As[64][32];
    __shared__ double Bs[64][64];
    int b = blockIdx.x, i0 = blockIdx.y * 32;
    int tid = threadIdx.x, c = tid & 63, rg = tid >> 6;
    const double* TIb = TI + b * 65536;
    const double* Zb = Z + b * 16384;
    double* Mb = M + b * 16384;
    double acc[8] = {};
    for (int k0 = (i0 >> 6) << 6; k0 < 256; k0 += 64) {
        for (int idx = tid; idx < 2048; idx += 256) {
            int kk = idx >> 5, ri = idx & 31;
            As[kk][ri] = TIb[(k0 + kk) * 256 + i0 + ri];
        }
        for (int idx = tid; idx < 4096; idx += 256) {
            int kk = idx >> 6, cc = idx & 63;
            Bs[kk][cc] = Zb[(k0 + kk) * 64 + cc];
        }
        __syncthreads();
        for (int kk = 0; kk < 64; ++kk) {
            double bv = Bs[kk][c];
#pragma unroll
            for (int r = 0; r < 8; ++r)
                acc[r] += As[kk][rg * 8 + r] * bv;
        }
        __syncthreads();
    }
#pragma unroll
    for (int r = 0; r < 8; ++r)
        Mb[(i0 + rg * 8 + r) * 64 + c] = acc[r];
}

// ---------------------------------------------------------------------------
// K5: W = PhiQ @ TinvF^T, PSUM[b][I][q] = sum_{i in I-tile} W[q][i]^2 (fp32)
// ---------------------------------------------------------------------------
__global__ __launch_bounds__(256) void k_spread_gemm(const float* __restrict__ PHIQ,
                                                     const float* __restrict__ TIF,
                                                     float* __restrict__ PSUM) {
    __shared__ float Qs[64][65];   // [q][k]
    __shared__ float Ts[64][65];   // [k][i]
    int b = blockIdx.x, q0 = blockIdx.y * 64, I = blockIdx.z, i0 = I * 64;
    int tid = threadIdx.x, tx = tid & 15, ty = tid >> 4;
    const float* Qb = PHIQ + b * (NQ * DIN) + q0 * DIN;
    const float* Tb = TIF + b * 65536;
    float acc[4][4];
#pragma unroll
    for (int r = 0; r < 4; ++r)
#pragma unroll
        for (int s = 0; s < 4; ++s) acc[r][s] = 0.0f;
    for (int k0 = 0; k0 <= i0; k0 += 64) {
        for (int idx = tid; idx < 4096; idx += 256) {
            int r = idx >> 6, c = idx & 63;
            Qs[r][c] = Qb[r * 256 + k0 + c];
            Ts[c][r] = Tb[(i0 + r) * 256 + k0 + c];
        }
        __syncthreads();
        for (int kk = 0; kk < 64; ++kk) {
            float a0 = Qs[4 * ty + 0][kk], a1 = Qs[4 * ty + 1][kk];
            float a2 = Qs[4 * ty + 2][kk], a3 = Qs[4 * ty + 3][kk];
            float b0 = Ts[kk][4 * tx + 0], b1 = Ts[kk][4 * tx + 1];
            float b2 = Ts[kk][4 * tx + 2], b3 = Ts[kk][4 * tx + 3];
            acc[0][0] += a0 * b0; acc[0][1] += a0 * b1; acc[0][2] += a0 * b2; acc[0][3] += a0 * b3;
            acc[1][0] += a1 * b0; acc[1][1] += a1 * b1; acc[1][2] += a1 * b2; acc[1][3] += a1 * b3;
            acc[2][0] += a2 * b0; acc[2][1] += a2 * b1; acc[2][2] += a2 * b2; acc[2][3] += a2 * b3;
            acc[3][0] += a3 * b0; acc[3][1] += a3 * b1; acc[3][2] += a3 * b2; acc[3][3] += a3 * b3;
        }
        __syncthreads();
    }
#pragma unroll
    for (int r = 0; r < 4; ++r) {
        float p = acc[r][0] * acc[r][0] + acc[r][1] * acc[r][1]
                + acc[r][2] * acc[r][2] + acc[r][3] * acc[r][3];
        p += __shfl_down(p, 8, 16);
        p += __shfl_down(p, 4, 16);
        p += __shfl_down(p, 2, 16);
        p += __shfl_down(p, 1, 16);
        if (tx == 0) PSUM[(size_t)(b * 4 + I) * 512 + q0 + 4 * ty + r] = p;
    }
}

// ---------------------------------------------------------------------------
// K6: mu = Phi_q @ m (fp32), FUSED epilogue: spread combine -> SPREAD,
//     nll partial (resid^2, logs) -> one fp64 atomicAdd per block.
// ---------------------------------------------------------------------------
__global__ __launch_bounds__(256) void k_mu_nll(const float* __restrict__ PHIQ,
                                                const double* __restrict__ M,
                                                const float* __restrict__ YQ,
                                                const float* __restrict__ PSUM,
                                                const float* __restrict__ SE,
                                                float* __restrict__ SPREAD,
                                                double* __restrict__ NLLACC,
                                                float* __restrict__ MU) {
    __shared__ float Qs[64][65];
    __shared__ float Ms[64][64];
    __shared__ double nred[64];
    int b = blockIdx.x, q0 = blockIdx.y * 64, tid = threadIdx.x;
    int tx = tid & 15, ty = tid >> 4;
    const float* Qb = PHIQ + b * (NQ * DIN) + q0 * DIN;
    const double* Mb = M + b * 16384;
    float acc[4][4];
#pragma unroll
    for (int r = 0; r < 4; ++r)
#pragma unroll
        for (int s = 0; s < 4; ++s) acc[r][s] = 0.0f;
    for (int c0 = 0; c0 < 256; c0 += 64) {
        for (int idx = tid; idx < 4096; idx += 256) {
            int r = idx >> 6, c = idx & 63;
            Qs[r][c] = Qb[r * 256 + c0 + c];
            Ms[r][c] = (float)Mb[(c0 + r) * 64 + c];
        }
        __syncthreads();
        for (int kk = 0; kk < 64; ++kk) {
            float a0 = Qs[4 * ty + 0][kk], a1 = Qs[4 * ty + 1][kk];
            float a2 = Qs[4 * ty + 2][kk], a3 = Qs[4 * ty + 3][kk];
            float b0 = Ms[kk][4 * tx + 0], b1 = Ms[kk][4 * tx + 1];
            float b2 = Ms[kk][4 * tx + 2], b3 = Ms[kk][4 * tx + 3];
            acc[0][0] += a0 * b0; acc[0][1] += a0 * b1; acc[0][2] += a0 * b2; acc[0][3] += a0 * b3;
            acc[1][0] += a1 * b0; acc[1][1] += a1 * b1; acc[1][2] += a1 * b2; acc[1][3] += a1 * b3;
            acc[2][0] += a2 * b0; acc[2][1] += a2 * b1; acc[2][2] += a2 * b2; acc[2][3] += a2 * b3;
            acc[3][0] += a3 * b0; acc[3][1] += a3 * b1; acc[3][2] += a3 * b2; acc[3][3] += a3 * b3;
        }
        __syncthreads();
    }
    float se = SE[0];
#pragma unroll
    for (int r = 0; r < 4; ++r) {
        int q = q0 + 4 * ty + r;
        float4 v = make_float4(acc[r][0], acc[r][1], acc[r][2], acc[r][3]);
        *(float4*)&MU[(b * NQ + q) * 64 + 4 * tx] = v;
        // nll partial for this row
        float4 y = *(const float4*)&YQ[(size_t)(b * NQ + q) * 64 + 4 * tx];
        float dx = y.x - v.x, dy = y.y - v.y, dz = y.z - v.z, dw = y.w - v.w;
        float qs = dx * dx + dy * dy + dz * dz + dw * dw;
        qs += __shfl_down(qs, 8, 16);
        qs += __shfl_down(qs, 4, 16);
        qs += __shfl_down(qs, 2, 16);
        qs += __shfl_down(qs, 1, 16);
        if (tx == 0) {
            float sp = 1.0f + PSUM[(size_t)(b * 4 + 0) * 512 + q]
                            + PSUM[(size_t)(b * 4 + 1) * 512 + q]
                            + PSUM[(size_t)(b * 4 + 2) * 512 + q]
                            + PSUM[(size_t)(b * 4 + 3) * 512 + q];
            SPREAD[b * 512 + q] = sp;
            float val = 64.0f * (logf(sp) + logf(se)) + qs / (sp * se);
            nred[ty * 4 + r] = (double)val;
        }
    }
    __syncthreads();
    for (int s = 32; s > 0; s >>= 1) {
        if (tid < s) nred[tid] += nred[tid + s];
        __syncthreads();
    }
    if (tid == 0) atomicAdd(NLLACC, nred[0] * (1.0 / 65536.0));
}

// ---------------------------------------------------------------------------
// K6b: write nll scalar
// ---------------------------------------------------------------------------
__global__ void k_nll_final(const double* __restrict__ NLLACC,
                            float* __restrict__ out) {
    if (threadIdx.x == 0) out[NLL_IDX] = (float)NLLACC[0];
}

// ---------------------------------------------------------------------------
// K7 (runs LAST): stream sig; fully overwrites scratch inside d_out sig region.
// ---------------------------------------------------------------------------
__global__ __launch_bounds__(256) void k_sig(const float* __restrict__ SPREAD,
                                             const float* __restrict__ SE,
                                             float* __restrict__ out) {
    __shared__ float sv_s;
    int bq = blockIdx.x, tid = threadIdx.x;
    if (tid == 0) sv_s = SPREAD[bq] * SE[0];
    __syncthreads();
    float sv = sv_s;
    float* base = out + (size_t)MU_SIZE + (size_t)bq * 4096;
    int i = tid >> 2;
    int jb = (tid & 3) << 4;
    int d = i - jb;
    float vals[16];
#pragma unroll
    for (int t = 0; t < 16; ++t) vals[t] = (t == d) ? sv : 0.0f;
    float4* p = (float4*)(base + tid * 16);
    p[0] = make_float4(vals[0], vals[1], vals[2], vals[3]);
    p[1] = make_float4(vals[4], vals[5], vals[6], vals[7]);
    p[2] = make_float4(vals[8], vals[9], vals[10], vals[11]);
    p[3] = make_float4(vals[12], vals[13], vals[14], vals[15]);
}

// ---------------------------------------------------------------------------
extern "C" void kernel_launch(void* const* d_in, const int* in_sizes, int n_in,
                              void* d_out, int out_size, void* d_ws, size_t ws_size,
                              hipStream_t stream) {
    const float* PHI_S = (const float*)d_in[0];
    const float* Y_S   = (const float*)d_in[1];
    const float* PHI_Q = (const float*)d_in[2];
    const float* Y_Q   = (const float*)d_in[3];
    const float* MP    = (const float*)d_in[4];
    const float* AP    = (const float*)d_in[5];
    const float* SE    = (const float*)d_in[6];
    float* out = (float*)d_out;

    // Big scratch inside sig region of d_out (dead before k_sig runs last).
    double* scratch = (double*)(out + MU_SIZE);
    double* G    = scratch;                    // 8,388,608 dbl (64 MB)
    double* LT   = G + 8388608;                // 8,388,608 dbl
    double* RHS  = LT + 8388608;               // 2,097,152 dbl (-> becomes M)
    double* Z    = RHS + 2097152;              // 2,097,152 dbl
    double* TI   = Z + 2097152;                // 8,388,608 dbl
    double* Spd  = TI + 8388608;               // 65,536 dbl
    double* MPN  = Spd + 65536;                // 16,384 dbl
    double* LI   = MPN + 16384;                // 2,097,152 dbl (16 MB, L11inv)
    float*  TIF  = (float*)(LI + 2097152);     // 8,388,608 f32 (32 MB)
    float*  PSUM = TIF + 8388608;              // 262,144 f32 (1 MB)
    // Small persistent scratch (survives until k_sig) in d_ws (proven 258 KB).
    float*  SPREAD = (float*)d_ws;                        // 65,536 f32
    double* NLLACC = (double*)((char*)d_ws + 65536 * 4);  // 1 dbl

    k_prior_sp   <<<256, 256, 0, stream>>>(AP, Spd, NLLACC);
    k_prior_mpn  <<<256, 64, 0, stream>>>(Spd, MP, MPN);
    k_build_G    <<<dim3(B_T, 10), 256, 0, stream>>>(PHI_S, Spd, G);
    k_build_rhs  <<<dim3(B_T, 4), 256, 0, stream>>>(PHI_S, Y_S, MPN, RHS);
    // blocked Cholesky at grid level, NB=64
    const int syrk_pairs[3] = {6, 3, 1};
    for (int kb = 0; kb < 4; ++kb) {
        k_potrf64<<<B_T, 256, 0, stream>>>(G, LT, LI, kb);
        if (kb < 3) {
            k_trsm64<<<dim3(B_T, 3 - kb), 256, 0, stream>>>(G, LI, LT, kb);
            k_syrk64<<<dim3(B_T, syrk_pairs[kb]), 256, 0, stream>>>(LT, G, kb);
        }
    }
    k_diaginv    <<<B_T, 256, 0, stream>>>(LT, TI, TIF);
    k_trinv      <<<dim3(B_T, 7), 256, 0, stream>>>(LT, TI, TIF);
    k_gemm_Z     <<<dim3(B_T, 8), 256, 0, stream>>>(TI, RHS, Z);
    k_gemm_M     <<<dim3(B_T, 8), 256, 0, stream>>>(TI, Z, RHS);
    k_spread_gemm<<<dim3(B_T, 8, 4), 256, 0, stream>>>(PHI_Q, TIF, PSUM);
    k_mu_nll     <<<dim3(B_T, 8), 256, 0, stream>>>(PHI_Q, RHS, Y_Q, PSUM, SE,
                                                    SPREAD, NLLACC, out);
    k_nll_final  <<<1, 64, 0, stream>>>(NLLACC, out);
    k_sig        <<<65536, 256, 0, stream>>>(SPREAD, SE, out);   // LAST
}

// Round 6
// 2074.099 us; speedup vs baseline: 1.3047x; 1.0075x over previous
//
#include <hip/hip_runtime.h>
#include <math.h>

#define B_T   128
#define NS    128
#define NQ    512
#define DIN   256
#define DOUT  64

#define MU_SIZE  (B_T*NQ*DOUT)            // 4,194,304 floats
#define SIG_SIZE (B_T*NQ*DOUT*DOUT)       // 268,435,456 floats
#define NLL_IDX  (MU_SIZE + SIG_SIZE)     // 272,629,760

typedef double v4df __attribute__((ext_vector_type(4)));

// D-layout candidates: value in (lane l, reg r) is D[lr][lc] with
//   fl=0: lr=4*(l>>4)+r, lc=l&15      (assumed / lab-notes)
//   fl=1: lr=(l>>4)+4*r, lc=l&15      (reg-major rows)
//   fl=2: lr=l&15, lc=4*(l>>4)+r      (transpose of 0)
//   fl=3: lr=l&15, lc=(l>>4)+4*r      (transpose of 1)
__device__ __forceinline__ void dmap(int fl, int kq, int mrow, int rr,
                                     int& lr, int& lc) {
    if (fl == 0)      { lr = kq * 4 + rr; lc = mrow; }
    else if (fl == 1) { lr = kq + 4 * rr; lc = mrow; }
    else if (fl == 2) { lr = mrow; lc = kq * 4 + rr; }
    else              { lr = mrow; lc = kq + 4 * rr; }
}

// ---------------------------------------------------------------------------
// PROBE: verify the f64 MFMA fragment contract on this hardware.
// A[i][k] = 1+i+2k (supplied as a = A[l&15][l>>4]);
// B[k][j] = 1+3j+5k (supplied as b = B[l>>4][l&15]).
// Exact-match D against the 4 candidates; flag 99 = none (scalar fallback).
// ---------------------------------------------------------------------------
__global__ void k_mfma_probe(double* __restrict__ FLAGD) {
    int l = threadIdx.x;
    int m = l & 15, q = l >> 4;
    double a = (double)(1 + m + 2 * q);
    double b = (double)(1 + 3 * m + 5 * q);
    v4df d = {0.0, 0.0, 0.0, 0.0};
    d = __builtin_amdgcn_mfma_f64_16x16x4f64(a, b, d, 0, 0, 0);
    bool ok0 = true, ok1 = true, ok2 = true, ok3 = true;
#pragma unroll
    for (int r = 0; r < 4; ++r) {
        int rows[4] = {4 * q + r, q + 4 * r, m, m};
        int cols[4] = {m, m, 4 * q + r, q + 4 * r};
        double ref[4];
#pragma unroll
        for (int v = 0; v < 4; ++v) {
            double s = 0.0;
#pragma unroll
            for (int k = 0; k < 4; ++k)
                s += (double)(1 + rows[v] + 2 * k) * (double)(1 + 3 * cols[v] + 5 * k);
            ref[v] = s;
        }
        if (d[r] != ref[0]) ok0 = false;
        if (d[r] != ref[1]) ok1 = false;
        if (d[r] != ref[2]) ok2 = false;
        if (d[r] != ref[3]) ok3 = false;
    }
    ok0 = __all(ok0); ok1 = __all(ok1); ok2 = __all(ok2); ok3 = __all(ok3);
    if (l == 0) {
        double f = 99.0;
        if (ok0) f = 0.0;
        else if (ok1) f = 1.0;
        else if (ok2) f = 2.0;
        else if (ok3) f = 3.0;
        FLAGD[0] = f;
    }
}

// ---------------------------------------------------------------------------
// K0a: Sp = A @ A^T  (fp64 accumulate); also zeroes the NLL accumulator.
// ---------------------------------------------------------------------------
__global__ __launch_bounds__(256) void k_prior_sp(const float* __restrict__ A,
                                                  double* __restrict__ Sp,
                                                  double* __restrict__ NLLACC) {
    __shared__ float Ai[16][260];
    __shared__ float Aj[16][260];
    int bi = blockIdx.x;
    int i0 = (bi >> 4) << 4;
    int j0 = (bi & 15) << 4;
    int tid = threadIdx.x;
    if (bi == 0 && tid == 0) NLLACC[0] = 0.0;
    for (int idx = tid; idx < 16 * 256; idx += 256) {
        int r = idx >> 8, c = idx & 255;
        Ai[r][c] = A[(i0 + r) * 256 + c];
        Aj[r][c] = A[(j0 + r) * 256 + c];
    }
    __syncthreads();
    int r = tid >> 4, c = tid & 15;
    double acc = 0.0;
    for (int k = 0; k < 256; ++k)
        acc += (double)Ai[r][k] * (double)Aj[c][k];
    Sp[(i0 + r) * 256 + (j0 + c)] = acc;
}

// ---------------------------------------------------------------------------
// K0b: MPN = Sp @ m_prior
// ---------------------------------------------------------------------------
__global__ __launch_bounds__(64) void k_prior_mpn(const double* __restrict__ Sp,
                                                  const float* __restrict__ MP,
                                                  double* __restrict__ MPN) {
    int i = blockIdx.x, k = threadIdx.x;
    double acc = 0.0;
    for (int t = 0; t < 256; ++t)
        acc += Sp[i * 256 + t] * (double)MP[t * 64 + k];
    MPN[i * 64 + k] = acc;
}

// ---------------------------------------------------------------------------
// K1: G_b = Phi_s^T Phi_s + Sp  (lower-triangle 64x64 tiles).
//     Dual-path: f64 MFMA (flag<4) or proven scalar (flag=99).
// ---------------------------------------------------------------------------
__global__ __launch_bounds__(256) void k_build_G(const float* __restrict__ PHI,
                                                 const double* __restrict__ Sp,
                                                 double* __restrict__ G,
                                                 const double* __restrict__ FLAGD) {
    __shared__ float As[128][64];
    __shared__ float Bs[128][64];
    int b = blockIdx.x;
    int by = blockIdx.y;
    int ti = 0;
    while (((ti + 1) * (ti + 2)) / 2 <= by) ti++;
    int tj = by - (ti * (ti + 1)) / 2;
    int i0 = ti * 64, j0 = tj * 64;
    int tid = threadIdx.x;
    const float* Pb = PHI + b * (NS * DIN);
    for (int idx = tid; idx < 128 * 64; idx += 256) {
        int n = idx >> 6, c = idx & 63;
        As[n][c] = Pb[n * 256 + i0 + c];
        Bs[n][c] = Pb[n * 256 + j0 + c];
    }
    __syncthreads();
    double* Gb = G + b * 65536;
    int fl = (int)FLAGD[0];
    if (fl < 4) {
        int lane = tid & 63, w = tid >> 6;
        int mrow = lane & 15, kq = lane >> 4;
        v4df acc[4];
#pragma unroll
        for (int t = 0; t < 4; ++t) acc[t] = (v4df){0.0, 0.0, 0.0, 0.0};
        for (int ks = 0; ks < 128; ks += 4) {
            double a = (double)As[ks + kq][w * 16 + mrow];
#pragma unroll
            for (int t = 0; t < 4; ++t) {
                double bb = (double)Bs[ks + kq][t * 16 + mrow];
                acc[t] = __builtin_amdgcn_mfma_f64_16x16x4f64(a, bb, acc[t], 0, 0, 0);
            }
        }
#pragma unroll
        for (int t = 0; t < 4; ++t) {
#pragma unroll
            for (int rr = 0; rr < 4; ++rr) {
                int lr, lc; dmap(fl, kq, mrow, rr, lr, lc);
                int i = i0 + w * 16 + lr;
                int j = j0 + t * 16 + lc;
                Gb[i * 256 + j] = acc[t][rr] + Sp[i * 256 + j];
            }
        }
    } else {
        int tx = tid & 15, ty = tid >> 4;
        double acc[4][4];
#pragma unroll
        for (int r = 0; r < 4; ++r)
#pragma unroll
            for (int s = 0; s < 4; ++s) acc[r][s] = 0.0;
        for (int n = 0; n < 128; ++n) {
            float a0 = As[n][4 * ty + 0], a1 = As[n][4 * ty + 1];
            float a2 = As[n][4 * ty + 2], a3 = As[n][4 * ty + 3];
            float b0 = Bs[n][4 * tx + 0], b1 = Bs[n][4 * tx + 1];
            float b2 = Bs[n][4 * tx + 2], b3 = Bs[n][4 * tx + 3];
            acc[0][0] += (double)a0 * b0; acc[0][1] += (double)a0 * b1;
            acc[0][2] += (double)a0 * b2; acc[0][3] += (double)a0 * b3;
            acc[1][0] += (double)a1 * b0; acc[1][1] += (double)a1 * b1;
            acc[1][2] += (double)a1 * b2; acc[1][3] += (double)a1 * b3;
            acc[2][0] += (double)a2 * b0; acc[2][1] += (double)a2 * b1;
            acc[2][2] += (double)a2 * b2; acc[2][3] += (double)a2 * b3;
            acc[3][0] += (double)a3 * b0; acc[3][1] += (double)a3 * b1;
            acc[3][2] += (double)a3 * b2; acc[3][3] += (double)a3 * b3;
        }
#pragma unroll
        for (int r = 0; r < 4; ++r) {
            int i = i0 + 4 * ty + r;
#pragma unroll
            for (int s = 0; s < 4; ++s) {
                int j = j0 + 4 * tx + s;
                Gb[i * 256 + j] = acc[r][s] + Sp[i * 256 + j];
            }
        }
    }
}

// ---------------------------------------------------------------------------
// K2: RHS_b = Phi_s^T Y_s + MPN  (dual-path)
// ---------------------------------------------------------------------------
__global__ __launch_bounds__(256) void k_build_rhs(const float* __restrict__ PHI,
                                                   const float* __restrict__ Y,
                                                   const double* __restrict__ MPN,
                                                   double* __restrict__ RHS,
                                                   const double* __restrict__ FLAGD) {
    __shared__ float As[128][64];
    __shared__ float Ys[128][64];
    int b = blockIdx.x, i0 = blockIdx.y * 64, tid = threadIdx.x;
    const float* Pb = PHI + b * (NS * DIN);
    const float* Yb = Y + b * (NS * DOUT);
    for (int idx = tid; idx < 128 * 64; idx += 256) {
        int n = idx >> 6, c = idx & 63;
        As[n][c] = Pb[n * 256 + i0 + c];
        Ys[n][c] = Yb[n * 64 + c];
    }
    __syncthreads();
    double* Rb = RHS + b * 16384;
    int fl = (int)FLAGD[0];
    if (fl < 4) {
        int lane = tid & 63, w = tid >> 6;
        int mrow = lane & 15, kq = lane >> 4;
        v4df acc[4];
#pragma unroll
        for (int t = 0; t < 4; ++t) acc[t] = (v4df){0.0, 0.0, 0.0, 0.0};
        for (int ks = 0; ks < 128; ks += 4) {
            double a = (double)As[ks + kq][w * 16 + mrow];
#pragma unroll
            for (int t = 0; t < 4; ++t) {
                double bb = (double)Ys[ks + kq][t * 16 + mrow];
                acc[t] = __builtin_amdgcn_mfma_f64_16x16x4f64(a, bb, acc[t], 0, 0, 0);
            }
        }
#pragma unroll
        for (int t = 0; t < 4; ++t) {
#pragma unroll
            for (int rr = 0; rr < 4; ++rr) {
                int lr, lc; dmap(fl, kq, mrow, rr, lr, lc);
                int i = i0 + w * 16 + lr;
                int kc = t * 16 + lc;
                Rb[i * 64 + kc] = acc[t][rr] + MPN[i * 64 + kc];
            }
        }
    } else {
        int tx = tid & 15, ty = tid >> 4;
        double acc[4][4];
#pragma unroll
        for (int r = 0; r < 4; ++r)
#pragma unroll
            for (int s = 0; s < 4; ++s) acc[r][s] = 0.0;
        for (int n = 0; n < 128; ++n) {
            float a0 = As[n][4 * ty + 0], a1 = As[n][4 * ty + 1];
            float a2 = As[n][4 * ty + 2], a3 = As[n][4 * ty + 3];
            float y0 = Ys[n][4 * tx + 0], y1 = Ys[n][4 * tx + 1];
            float y2 = Ys[n][4 * tx + 2], y3 = Ys[n][4 * tx + 3];
            acc[0][0] += (double)a0 * y0; acc[0][1] += (double)a0 * y1;
            acc[0][2] += (double)a0 * y2; acc[0][3] += (double)a0 * y3;
            acc[1][0] += (double)a1 * y0; acc[1][1] += (double)a1 * y1;
            acc[1][2] += (double)a1 * y2; acc[1][3] += (double)a1 * y3;
            acc[2][0] += (double)a2 * y0; acc[2][1] += (double)a2 * y1;
            acc[2][2] += (double)a2 * y2; acc[2][3] += (double)a2 * y3;
            acc[3][0] += (double)a3 * y0; acc[3][1] += (double)a3 * y1;
            acc[3][2] += (double)a3 * y2; acc[3][3] += (double)a3 * y3;
        }
#pragma unroll
        for (int r = 0; r < 4; ++r) {
            int i = i0 + 4 * ty + r;
#pragma unroll
            for (int s = 0; s < 4; ++s) {
                int kc = 4 * tx + s;
                Rb[i * 64 + kc] = acc[r][s] + MPN[i * 64 + kc];
            }
        }
    }
}

// ---------------------------------------------------------------------------
// K3a: POTRF64 — factor 64x64 diag block kb of G in LDS (proven, unchanged).
// ---------------------------------------------------------------------------
__global__ __launch_bounds__(256) void k_potrf64(const double* __restrict__ G,
                                                 double* __restrict__ LT,
                                                 double* __restrict__ LI,
                                                 int kb) {
    __shared__ double D[64][65];
    __shared__ double T[64][33];
    __shared__ double C[32][33];
    __shared__ double L11s[16 * 17];
    __shared__ double DINVs[16];
    int b = blockIdx.x, tid = threadIdx.x;
    int o = kb * 64;
    const double* Gb = G + b * 65536;
    double* LTb = LT + b * 65536;
    double* LIb = LI + b * 16384 + kb * 4096;
    for (int idx = tid; idx < 4096; idx += 256) {
        int r = idx >> 6, c = idx & 63;
        D[r][c] = Gb[(o + r) * 256 + o + c];
    }
    __syncthreads();
    for (int p0 = 0; p0 < 64; p0 += 16) {
        if (tid < 64) {
            int lane = tid;
            double a[16];
            if (lane < 16) {
#pragma unroll
                for (int p = 0; p < 16; ++p) a[p] = D[p0 + lane][p0 + p];
            }
#pragma unroll
            for (int p = 0; p < 16; ++p) {
                double dp = __shfl(a[p], p);
                double d = sqrt(fmax(dp, 1e-300));
                double inv = 1.0 / d;
                if (lane == p) { a[p] = d; DINVs[p] = inv; }
                else if (lane > p) a[p] *= inv;
#pragma unroll
                for (int p2 = p + 1; p2 < 16; ++p2) {
                    double cc = __shfl(a[p], p2);
                    if (lane > p) a[p2] -= a[p] * cc;
                }
            }
            if (lane < 16) {
#pragma unroll
                for (int p = 0; p < 16; ++p) {
                    if (p <= lane) {
                        L11s[lane * 17 + p] = a[p];
                        D[p0 + lane][p0 + p] = a[p];
                    }
                }
            }
        }
        __syncthreads();
        int nsolve = 48 - p0;
        if (tid < nsolve) {
            int rr = p0 + 16 + tid;
            double x[16];
#pragma unroll
            for (int p = 0; p < 16; ++p) {
                double s = D[rr][p0 + p];
#pragma unroll
                for (int p2 = 0; p2 < 16; ++p2) {
                    if (p2 < p) s -= L11s[p * 17 + p2] * x[p2];
                }
                x[p] = s * DINVs[p];
                D[rr][p0 + p] = x[p];
            }
        }
        __syncthreads();
        int rem = nsolve;
        for (int idx = tid; idx < rem * rem; idx += 256) {
            int i2 = idx / rem, j2 = idx - i2 * rem;
            if (j2 <= i2) {
                int i = p0 + 16 + i2, j = p0 + 16 + j2;
                double s = 0.0;
#pragma unroll
                for (int p = 0; p < 16; ++p) s += D[i][p0 + p] * D[j][p0 + p];
                D[i][j] -= s;
            }
        }
        __syncthreads();
    }
    for (int idx = tid; idx < 4096; idx += 256) {
        int c = idx >> 6, r = idx & 63;
        if (r >= c) LTb[(o + c) * 256 + (o + r)] = D[r][c];
    }
    if (tid < 64) {
        int g = tid >> 5, j = tid & 31;
        int off = g * 32;
        double x[32];
#pragma unroll
        for (int i = 0; i < 32; ++i) {
            double s = (i == j) ? 1.0 : 0.0;
#pragma unroll
            for (int k = 0; k < i; ++k) {
                double lv = D[off + i][off + k];
                s -= (k >= j) ? lv * x[k] : 0.0;
            }
            double inv = 1.0 / D[off + i][off + i];
            x[i] = (i >= j) ? s * inv : 0.0;
        }
#pragma unroll
        for (int i = 0; i < 32; ++i) T[off + i][j] = x[i];
    }
    __syncthreads();
    for (int idx = tid; idx < 1024; idx += 256) {
        int r = idx >> 5, c = idx & 31;
        double s = 0.0;
#pragma unroll
        for (int p = 0; p < 32; ++p) s += D[32 + r][p] * T[p][c];
        C[r][c] = s;
    }
    __syncthreads();
    for (int idx = tid; idx < 1024; idx += 256) {
        int r = idx >> 5, c = idx & 31;
        double s = 0.0;
#pragma unroll
        for (int p = 0; p < 32; ++p) s += T[32 + r][p] * C[p][c];
        D[32 + r][c] = -s;
    }
    __syncthreads();
    for (int idx = tid; idx < 4096; idx += 256) {
        int p = idx >> 6, c = idx & 63;
        double v;
        if (c < 32) v = (p < 32) ? T[c][p] : 0.0;
        else        v = (p < 32) ? D[c][p] : T[c][p - 32];
        LIb[p * 64 + c] = v;
    }
}

// ---------------------------------------------------------------------------
// K3a': TRSM64 — L21 = G21 @ L11^{-T} (dual-path 64x64x64 GEMM).
// ---------------------------------------------------------------------------
__global__ __launch_bounds__(256) void k_trsm64(const double* __restrict__ G,
                                                const double* __restrict__ LI,
                                                double* __restrict__ LT,
                                                int kb,
                                                const double* __restrict__ FLAGD) {
    __shared__ double Gs[64][65];   // [r][k]
    __shared__ double Ls[64][65];   // [k][c] = Linv^T
    int b = blockIdx.x;
    int i0 = (kb + 1 + blockIdx.y) * 64;
    int o = kb * 64;
    int tid = threadIdx.x;
    const double* Gb = G + b * 65536;
    const double* LIb = LI + b * 16384 + kb * 4096;
    double* LTb = LT + b * 65536;
    for (int idx = tid; idx < 4096; idx += 256) {
        int r = idx >> 6, c = idx & 63;
        Gs[r][c] = Gb[(i0 + r) * 256 + o + c];
        Ls[r][c] = LIb[idx];
    }
    __syncthreads();
    int fl = (int)FLAGD[0];
    if (fl < 4) {
        int lane = tid & 63, w = tid >> 6;
        int mrow = lane & 15, kq = lane >> 4;
        v4df acc[4];
#pragma unroll
        for (int t = 0; t < 4; ++t) acc[t] = (v4df){0.0, 0.0, 0.0, 0.0};
        for (int ks = 0; ks < 64; ks += 4) {
            double a = Gs[w * 16 + mrow][ks + kq];
#pragma unroll
            for (int t = 0; t < 4; ++t) {
                double bb = Ls[ks + kq][t * 16 + mrow];
                acc[t] = __builtin_amdgcn_mfma_f64_16x16x4f64(a, bb, acc[t], 0, 0, 0);
            }
        }
#pragma unroll
        for (int t = 0; t < 4; ++t) {
#pragma unroll
            for (int rr = 0; rr < 4; ++rr) {
                int lr, lc; dmap(fl, kq, mrow, rr, lr, lc);
                int r = w * 16 + lr;
                int c = t * 16 + lc;
                LTb[(o + c) * 256 + i0 + r] = acc[t][rr];
            }
        }
    } else {
        int tx = tid & 15, ty = tid >> 4;
        double acc[4][4];
#pragma unroll
        for (int r = 0; r < 4; ++r)
#pragma unroll
            for (int s = 0; s < 4; ++s) acc[r][s] = 0.0;
        for (int kk = 0; kk < 64; ++kk) {
            double a0 = Gs[4 * ty + 0][kk], a1 = Gs[4 * ty + 1][kk];
            double a2 = Gs[4 * ty + 2][kk], a3 = Gs[4 * ty + 3][kk];
            double b0 = Ls[kk][4 * tx + 0], b1 = Ls[kk][4 * tx + 1];
            double b2 = Ls[kk][4 * tx + 2], b3 = Ls[kk][4 * tx + 3];
            acc[0][0] += a0 * b0; acc[0][1] += a0 * b1; acc[0][2] += a0 * b2; acc[0][3] += a0 * b3;
            acc[1][0] += a1 * b0; acc[1][1] += a1 * b1; acc[1][2] += a1 * b2; acc[1][3] += a1 * b3;
            acc[2][0] += a2 * b0; acc[2][1] += a2 * b1; acc[2][2] += a2 * b2; acc[2][3] += a2 * b3;
            acc[3][0] += a3 * b0; acc[3][1] += a3 * b1; acc[3][2] += a3 * b2; acc[3][3] += a3 * b3;
        }
#pragma unroll
        for (int r = 0; r < 4; ++r)
#pragma unroll
            for (int s = 0; s < 4; ++s)
                LTb[(o + 4 * tx + s) * 256 + i0 + 4 * ty + r] = acc[r][s];
    }
}

// ---------------------------------------------------------------------------
// K3a'': SYRK64 — G[i,j] -= L21[i] @ L21[j]^T (dual-path).
// ---------------------------------------------------------------------------
__global__ __launch_bounds__(256) void k_syrk64(const double* __restrict__ LT,
                                                double* __restrict__ G,
                                                int kb,
                                                const double* __restrict__ FLAGD) {
    __shared__ double LiT[64][65];  // [k][r]
    __shared__ double LjT[64][65];  // [k][c]
    int b = blockIdx.x, py = blockIdx.y;
    int ti = 0;
    while (((ti + 1) * (ti + 2)) / 2 <= py) ti++;
    int tj = py - (ti * (ti + 1)) / 2;
    int i0 = (kb + 1 + ti) * 64, j0 = (kb + 1 + tj) * 64;
    int o = kb * 64;
    int tid = threadIdx.x;
    const double* LTb = LT + b * 65536;
    double* Gb = G + b * 65536;
    for (int idx = tid; idx < 4096; idx += 256) {
        int p = idx >> 6, r = idx & 63;
        LiT[p][r] = LTb[(o + p) * 256 + i0 + r];
        LjT[p][r] = LTb[(o + p) * 256 + j0 + r];
    }
    __syncthreads();
    int fl = (int)FLAGD[0];
    if (fl < 4) {
        int lane = tid & 63, w = tid >> 6;
        int mrow = lane & 15, kq = lane >> 4;
        v4df acc[4];
#pragma unroll
        for (int t = 0; t < 4; ++t) acc[t] = (v4df){0.0, 0.0, 0.0, 0.0};
        for (int ks = 0; ks < 64; ks += 4) {
            double a = LiT[ks + kq][w * 16 + mrow];
#pragma unroll
            for (int t = 0; t < 4; ++t) {
                double bb = LjT[ks + kq][t * 16 + mrow];
                acc[t] = __builtin_amdgcn_mfma_f64_16x16x4f64(a, bb, acc[t], 0, 0, 0);
            }
        }
#pragma unroll
        for (int t = 0; t < 4; ++t) {
#pragma unroll
            for (int rr = 0; rr < 4; ++rr) {
                int lr, lc; dmap(fl, kq, mrow, rr, lr, lc);
                int gi = i0 + w * 16 + lr;
                int gj = j0 + t * 16 + lc;
                Gb[gi * 256 + gj] -= acc[t][rr];
            }
        }
    } else {
        int tx = tid & 15, ty = tid >> 4;
        double acc[4][4];
#pragma unroll
        for (int r = 0; r < 4; ++r)
#pragma unroll
            for (int s = 0; s < 4; ++s) acc[r][s] = 0.0;
        for (int kk = 0; kk < 64; ++kk) {
            double a0 = LiT[kk][4 * ty + 0], a1 = LiT[kk][4 * ty + 1];
            double a2 = LiT[kk][4 * ty + 2], a3 = LiT[kk][4 * ty + 3];
            double b0 = LjT[kk][4 * tx + 0], b1 = LjT[kk][4 * tx + 1];
            double b2 = LjT[kk][4 * tx + 2], b3 = LjT[kk][4 * tx + 3];
            acc[0][0] += a0 * b0; acc[0][1] += a0 * b1; acc[0][2] += a0 * b2; acc[0][3] += a0 * b3;
            acc[1][0] += a1 * b0; acc[1][1] += a1 * b1; acc[1][2] += a1 * b2; acc[1][3] += a1 * b3;
            acc[2][0] += a2 * b0; acc[2][1] += a2 * b1; acc[2][2] += a2 * b2; acc[2][3] += a2 * b3;
            acc[3][0] += a3 * b0; acc[3][1] += a3 * b1; acc[3][2] += a3 * b2; acc[3][3] += a3 * b3;
        }
#pragma unroll
        for (int r = 0; r < 4; ++r) {
            int gi = i0 + 4 * ty + r;
#pragma unroll
            for (int s = 0; s < 4; ++s) {
                int gj = j0 + 4 * tx + s;
                Gb[gi * 256 + gj] -= acc[r][s];
            }
        }
    }
}

// ---------------------------------------------------------------------------
// K3b: zero upper triangle of TI/TIF; invert the 8 diagonal 32x32 blocks of L.
// ---------------------------------------------------------------------------
__global__ __launch_bounds__(256) void k_diaginv(const double* __restrict__ LT,
                                                 double* __restrict__ TI,
                                                 float* __restrict__ TIF) {
    __shared__ double SHD[8192];
    int b = blockIdx.x, tid = threadIdx.x;
    const double* LTb = LT + b * 65536;
    double* TIb = TI + b * 65536;
    float* TIFb = TIF + b * 65536;
    for (int idx = tid; idx < 65536; idx += 256) {
        int i = idx >> 8, k = idx & 255;
        if (k > i) { TIb[idx] = 0.0; TIFb[idx] = 0.0f; }
    }
    for (int idx = tid; idx < 8192; idx += 256) {
        int g = idx >> 10, rem = idx & 1023, k = rem >> 5, i = rem & 31;
        SHD[idx] = LTb[(32 * g + k) * 256 + 32 * g + i];
    }
    __syncthreads();
    int g = tid >> 5, j = tid & 31;
    const double* D = SHD + g * 1024;
    double x[32];
#pragma unroll
    for (int i = 0; i < 32; ++i) {
        double s = (i == j) ? 1.0 : 0.0;
#pragma unroll
        for (int k = 0; k < i; ++k) {
            double lv = D[k * 32 + i];
            s -= (k >= j) ? lv * x[k] : 0.0;
        }
        double inv = 1.0 / D[i * 32 + i];
        x[i] = (i >= j) ? s * inv : 0.0;
    }
#pragma unroll
    for (int i = 0; i < 32; ++i) {
        int gi = 32 * g + i, gj = 32 * g + j;
        TIb[gi * 256 + gj] = x[i];
        TIFb[gi * 256 + gj] = (float)x[i];
    }
}

// ---------------------------------------------------------------------------
// K3c: off-diagonal trinv sweep, COLUMN-BLOCK PARALLEL.
// ---------------------------------------------------------------------------
__global__ __launch_bounds__(256) void k_trinv(const double* __restrict__ LT,
                                               double* __restrict__ TI,
                                               float* __restrict__ TIF) {
    __shared__ double XS[8][1024];
    int b = blockIdx.x, J = blockIdx.y;
    int tid = threadIdx.x, j = tid & 31, ig = tid >> 5;
    const double* LTb = LT + b * 65536;
    double* TIb = TI + b * 65536;
    float* TIFb = TIF + b * 65536;
    double* Bsh = XS[7];

    for (int idx = tid; idx < 1024; idx += 256) {
        int kk = idx >> 5, c = idx & 31;
        XS[J][idx] = TIb[(32 * J + kk) * 256 + 32 * J + c];
    }
    __syncthreads();

    for (int I = J + 1; I < 8; ++I) {
        double acc[4] = {0.0, 0.0, 0.0, 0.0};
        for (int K = J; K < I; ++K) {
            for (int idx = tid; idx < 1024; idx += 256) {
                int kk = idx >> 5, i2 = idx & 31;
                Bsh[idx] = LTb[(32 * K + kk) * 256 + 32 * I + i2];
            }
            __syncthreads();
            const double* Xk = XS[K];
            for (int kk = 0; kk < 32; ++kk) {
                double tv = Xk[kk * 32 + j];
#pragma unroll
                for (int r = 0; r < 4; ++r)
                    acc[r] += Bsh[kk * 32 + ig * 4 + r] * tv;
            }
            __syncthreads();
        }
#pragma unroll
        for (int r = 0; r < 4; ++r) Bsh[(ig * 4 + r) * 32 + j] = acc[r];
        __syncthreads();
        double c[4] = {0.0, 0.0, 0.0, 0.0};
        for (int k = 0; k < 32; ++k) {
            double bv = Bsh[k * 32 + j];
#pragma unroll
            for (int r = 0; r < 4; ++r)
                c[r] -= TIb[(32 * I + ig * 4 + r) * 256 + 32 * I + k] * bv;
        }
#pragma unroll
        for (int r = 0; r < 4; ++r) {
            int gi = 32 * I + ig * 4 + r, gj = 32 * J + j;
            TIb[gi * 256 + gj] = c[r];
            TIFb[gi * 256 + gj] = (float)c[r];
            if (I < 7) XS[I][(ig * 4 + r) * 32 + j] = c[r];
        }
        __syncthreads();
    }
}

// ---------------------------------------------------------------------------
// K4a: Z = Tinv @ RHS  (dual-path, 64-row tiles, triangular k-skip)
// ---------------------------------------------------------------------------
__global__ __launch_bounds__(256) void k_gemm_Z(const double* __restrict__ TI,
                                                const double* __restrict__ RHS,
                                                double* __restrict__ Z,
                                                const double* __restrict__ FLAGD) {
    __shared__ double As[64][65];   // [m][k]
    __shared__ double Bs[64][65];   // [k][c]
    int b = blockIdx.x, i0 = blockIdx.y * 64;
    int tid = threadIdx.x;
    const double* TIb = TI + b * 65536;
    const double* Rb = RHS + b * 16384;
    double* Zb = Z + b * 16384;
    int fl = (int)FLAGD[0];
    if (fl < 4) {
        int lane = tid & 63, w = tid >> 6;
        int mrow = lane & 15, kq = lane >> 4;
        v4df acc[4];
#pragma unroll
        for (int t = 0; t < 4; ++t) acc[t] = (v4df){0.0, 0.0, 0.0, 0.0};
        for (int k0 = 0; k0 <= i0; k0 += 64) {
            for (int idx = tid; idx < 4096; idx += 256) {
                int r = idx >> 6, kk = idx & 63;
                As[r][kk] = TIb[(i0 + r) * 256 + k0 + kk];
                Bs[r][kk] = Rb[(k0 + r) * 64 + kk];
            }
            __syncthreads();
            for (int ks = 0; ks < 64; ks += 4) {
                double a = As[w * 16 + mrow][ks + kq];
#pragma unroll
                for (int t = 0; t < 4; ++t) {
                    double bb = Bs[ks + kq][t * 16 + mrow];
                    acc[t] = __builtin_amdgcn_mfma_f64_16x16x4f64(a, bb, acc[t], 0, 0, 0);
                }
            }
            __syncthreads();
        }
#pragma unroll
        for (int t = 0; t < 4; ++t) {
#pragma unroll
            for (int rr = 0; rr < 4; ++rr) {
                int lr, lc; dmap(fl, kq, mrow, rr, lr, lc);
                Zb[(i0 + w * 16 + lr) * 64 + t * 16 + lc] = acc[t][rr];
            }
        }
    } else {
        int c = tid & 63, rg = tid >> 6;
        double acc[16];
#pragma unroll
        for (int r = 0; r < 16; ++r) acc[r] = 0.0;
        for (int k0 = 0; k0 <= i0; k0 += 64) {
            for (int idx = tid; idx < 4096; idx += 256) {
                int r = idx >> 6, kk = idx & 63;
                As[r][kk] = TIb[(i0 + r) * 256 + k0 + kk];
                Bs[r][kk] = Rb[(k0 + r) * 64 + kk];
            }
            __syncthreads();
            for (int kk = 0; kk < 64; ++kk) {
                double bv = Bs[kk][c];
#pragma unroll
                for (int r = 0; r < 16; ++r)
                    acc[r] += As[rg * 16 + r][kk] * bv;
            }
            __syncthreads();
        }
#pragma unroll
        for (int r = 0; r < 16; ++r)
            Zb[(i0 + rg * 16 + r) * 64 + c] = acc[r];
    }
}

// ---------------------------------------------------------------------------
// K4b: M = Tinv^T @ Z  (dual-path, 64-row tiles, triangular k-skip)
// ---------------------------------------------------------------------------
__global__ __launch_bounds__(256) void k_gemm_M(const double* __restrict__ TI,
                                                const double* __restrict__ Z,
                                                double* __restrict__ M,
                                                const double* __restrict__ FLAGD) {
    __shared__ double As[64][65];   // [k][m]
    __shared__ double Bs[64][65];   // [k][c]
    int b = blockIdx.x, i0 = blockIdx.y * 64;
    int tid = threadIdx.x;
    const double* TIb = TI + b * 65536;
    const double* Zb = Z + b * 16384;
    double* Mb = M + b * 16384;
    int fl = (int)FLAGD[0];
    if (fl < 4) {
        int lane = tid & 63, w = tid >> 6;
        int mrow = lane & 15, kq = lane >> 4;
        v4df acc[4];
#pragma unroll
        for (int t = 0; t < 4; ++t) acc[t] = (v4df){0.0, 0.0, 0.0, 0.0};
        for (int k0 = i0; k0 < 256; k0 += 64) {
            for (int idx = tid; idx < 4096; idx += 256) {
                int kk = idx >> 6, m = idx & 63;
                As[kk][m] = TIb[(k0 + kk) * 256 + i0 + m];
                Bs[kk][m] = Zb[(k0 + kk) * 64 + m];
            }
            __syncthreads();
            for (int ks = 0; ks < 64; ks += 4) {
                double a = As[ks + kq][w * 16 + mrow];
#pragma unroll
                for (int t = 0; t < 4; ++t) {
                    double bb = Bs[ks + kq][t * 16 + mrow];
                    acc[t] = __builtin_amdgcn_mfma_f64_16x16x4f64(a, bb, acc[t], 0, 0, 0);
                }
            }
            __syncthreads();
        }
#pragma unroll
        for (int t = 0; t < 4; ++t) {
#pragma unroll
            for (int rr = 0; rr < 4; ++rr) {
                int lr, lc; dmap(fl, kq, mrow, rr, lr, lc);
                Mb[(i0 + w * 16 + lr) * 64 + t * 16 + lc] = acc[t][rr];
            }
        }
    } else {
        int c = tid & 63, rg = tid >> 6;
        double acc[16];
#pragma unroll
        for (int r = 0; r < 16; ++r) acc[r] = 0.0;
        for (int k0 = i0; k0 < 256; k0 += 64) {
            for (int idx = tid; idx < 4096; idx += 256) {
                int kk = idx >> 6, m = idx & 63;
                As[kk][m] = TIb[(k0 + kk) * 256 + i0 + m];
                Bs[kk][m] = Zb[(k0 + kk) * 64 + m];
            }
            __syncthreads();
            for (int kk = 0; kk < 64; ++kk) {
                double bv = Bs[kk][c];
#pragma unroll
                for (int r = 0; r < 16; ++r)
                    acc[r] += As[kk][rg * 16 + r] * bv;
            }
            __syncthreads();
        }
#pragma unroll
        for (int r = 0; r < 16; ++r)
            Mb[(i0 + rg * 16 + r) * 64 + c] = acc[r];
    }
}

// ---------------------------------------------------------------------------
// K5: W = PhiQ @ TinvF^T, PSUM[b][I][q] = sum_{i in I-tile} W[q][i]^2 (fp32)
// ---------------------------------------------------------------------------
__global__ __launch_bounds__(256) void k_spread_gemm(const float* __restrict__ PHIQ,
                                                     const float* __restrict__ TIF,
                                                     float* __restrict__ PSUM) {
    __shared__ float Qs[64][65];
    __shared__ float Ts[64][65];
    int b = blockIdx.x, q0 = blockIdx.y * 64, I = blockIdx.z, i0 = I * 64;
    int tid = threadIdx.x, tx = tid & 15, ty = tid >> 4;
    const float* Qb = PHIQ + b * (NQ * DIN) + q0 * DIN;
    const float* Tb = TIF + b * 65536;
    float acc[4][4];
#pragma unroll
    for (int r = 0; r < 4; ++r)
#pragma unroll
        for (int s = 0; s < 4; ++s) acc[r][s] = 0.0f;
    for (int k0 = 0; k0 <= i0; k0 += 64) {
        for (int idx = tid; idx < 4096; idx += 256) {
            int r = idx >> 6, c = idx & 63;
            Qs[r][c] = Qb[r * 256 + k0 + c];
            Ts[c][r] = Tb[(i0 + r) * 256 + k0 + c];
        }
        __syncthreads();
        for (int kk = 0; kk < 64; ++kk) {
            float a0 = Qs[4 * ty + 0][kk], a1 = Qs[4 * ty + 1][kk];
            float a2 = Qs[4 * ty + 2][kk], a3 = Qs[4 * ty + 3][kk];
            float b0 = Ts[kk][4 * tx + 0], b1 = Ts[kk][4 * tx + 1];
            float b2 = Ts[kk][4 * tx + 2], b3 = Ts[kk][4 * tx + 3];
            acc[0][0] += a0 * b0; acc[0][1] += a0 * b1; acc[0][2] += a0 * b2; acc[0][3] += a0 * b3;
            acc[1][0] += a1 * b0; acc[1][1] += a1 * b1; acc[1][2] += a1 * b2; acc[1][3] += a1 * b3;
            acc[2][0] += a2 * b0; acc[2][1] += a2 * b1; acc[2][2] += a2 * b2; acc[2][3] += a2 * b3;
            acc[3][0] += a3 * b0; acc[3][1] += a3 * b1; acc[3][2] += a3 * b2; acc[3][3] += a3 * b3;
        }
        __syncthreads();
    }
#pragma unroll
    for (int r = 0; r < 4; ++r) {
        float p = acc[r][0] * acc[r][0] + acc[r][1] * acc[r][1]
                + acc[r][2] * acc[r][2] + acc[r][3] * acc[r][3];
        p += __shfl_down(p, 8, 16);
        p += __shfl_down(p, 4, 16);
        p += __shfl_down(p, 2, 16);
        p += __shfl_down(p, 1, 16);
        if (tx == 0) PSUM[(size_t)(b * 4 + I) * 512 + q0 + 4 * ty + r] = p;
    }
}

// ---------------------------------------------------------------------------
// K6: mu = Phi_q @ m (fp32), FUSED epilogue: spread combine -> SPREAD,
//     nll partial -> one fp64 atomicAdd per block.
// ---------------------------------------------------------------------------
__global__ __launch_bounds__(256) void k_mu_nll(const float* __restrict__ PHIQ,
                                                const double* __restrict__ M,
                                                const float* __restrict__ YQ,
                                                const float* __restrict__ PSUM,
                                                const float* __restrict__ SE,
                                                float* __restrict__ SPREAD,
                                                double* __restrict__ NLLACC,
                                                float* __restrict__ MU) {
    __shared__ float Qs[64][65];
    __shared__ float Ms[64][64];
    __shared__ double nred[64];
    int b = blockIdx.x, q0 = blockIdx.y * 64, tid = threadIdx.x;
    int tx = tid & 15, ty = tid >> 4;
    const float* Qb = PHIQ + b * (NQ * DIN) + q0 * DIN;
    const double* Mb = M + b * 16384;
    float acc[4][4];
#pragma unroll
    for (int r = 0; r < 4; ++r)
#pragma unroll
        for (int s = 0; s < 4; ++s) acc[r][s] = 0.0f;
    for (int c0 = 0; c0 < 256; c0 += 64) {
        for (int idx = tid; idx < 4096; idx += 256) {
            int r = idx >> 6, c = idx & 63;
            Qs[r][c] = Qb[r * 256 + c0 + c];
            Ms[r][c] = (float)Mb[(c0 + r) * 64 + c];
        }
        __syncthreads();
        for (int kk = 0; kk < 64; ++kk) {
            float a0 = Qs[4 * ty + 0][kk], a1 = Qs[4 * ty + 1][kk];
            float a2 = Qs[4 * ty + 2][kk], a3 = Qs[4 * ty + 3][kk];
            float b0 = Ms[kk][4 * tx + 0], b1 = Ms[kk][4 * tx + 1];
            float b2 = Ms[kk][4 * tx + 2], b3 = Ms[kk][4 * tx + 3];
            acc[0][0] += a0 * b0; acc[0][1] += a0 * b1; acc[0][2] += a0 * b2; acc[0][3] += a0 * b3;
            acc[1][0] += a1 * b0; acc[1][1] += a1 * b1; acc[1][2] += a1 * b2; acc[1][3] += a1 * b3;
            acc[2][0] += a2 * b0; acc[2][1] += a2 * b1; acc[2][2] += a2 * b2; acc[2][3] += a2 * b3;
            acc[3][0] += a3 * b0; acc[3][1] += a3 * b1; acc[3][2] += a3 * b2; acc[3][3] += a3 * b3;
        }
        __syncthreads();
    }
    float se = SE[0];
#pragma unroll
    for (int r = 0; r < 4; ++r) {
        int q = q0 + 4 * ty + r;
        float4 v = make_float4(acc[r][0], acc[r][1], acc[r][2], acc[r][3]);
        *(float4*)&MU[(b * NQ + q) * 64 + 4 * tx] = v;
        float4 y = *(const float4*)&YQ[(size_t)(b * NQ + q) * 64 + 4 * tx];
        float dx = y.x - v.x, dy = y.y - v.y, dz = y.z - v.z, dw = y.w - v.w;
        float qs = dx * dx + dy * dy + dz * dz + dw * dw;
        qs += __shfl_down(qs, 8, 16);
        qs += __shfl_down(qs, 4, 16);
        qs += __shfl_down(qs, 2, 16);
        qs += __shfl_down(qs, 1, 16);
        if (tx == 0) {
            float sp = 1.0f + PSUM[(size_t)(b * 4 + 0) * 512 + q]
                            + PSUM[(size_t)(b * 4 + 1) * 512 + q]
                            + PSUM[(size_t)(b * 4 + 2) * 512 + q]
                            + PSUM[(size_t)(b * 4 + 3) * 512 + q];
            SPREAD[b * 512 + q] = sp;
            float val = 64.0f * (logf(sp) + logf(se)) + qs / (sp * se);
            nred[ty * 4 + r] = (double)val;
        }
    }
    __syncthreads();
    for (int s = 32; s > 0; s >>= 1) {
        if (tid < s) nred[tid] += nred[tid + s];
        __syncthreads();
    }
    if (tid == 0) atomicAdd(NLLACC, nred[0] * (1.0 / 65536.0));
}

// ---------------------------------------------------------------------------
// K6b: write nll scalar
// ---------------------------------------------------------------------------
__global__ void k_nll_final(const double* __restrict__ NLLACC,
                            float* __restrict__ out) {
    if (threadIdx.x == 0) out[NLL_IDX] = (float)NLLACC[0];
}

// ---------------------------------------------------------------------------
// K7 (runs LAST): stream sig; fully overwrites scratch inside d_out sig region.
// ---------------------------------------------------------------------------
__global__ __launch_bounds__(256) void k_sig(const float* __restrict__ SPREAD,
                                             const float* __restrict__ SE,
                                             float* __restrict__ out) {
    __shared__ float sv_s;
    int bq = blockIdx.x, tid = threadIdx.x;
    if (tid == 0) sv_s = SPREAD[bq] * SE[0];
    __syncthreads();
    float sv = sv_s;
    float* base = out + (size_t)MU_SIZE + (size_t)bq * 4096;
    int i = tid >> 2;
    int jb = (tid & 3) << 4;
    int d = i - jb;
    float vals[16];
#pragma unroll
    for (int t = 0; t < 16; ++t) vals[t] = (t == d) ? sv : 0.0f;
    float4* p = (float4*)(base + tid * 16);
    p[0] = make_float4(vals[0], vals[1], vals[2], vals[3]);
    p[1] = make_float4(vals[4], vals[5], vals[6], vals[7]);
    p[2] = make_float4(vals[8], vals[9], vals[10], vals[11]);
    p[3] = make_float4(vals[12], vals[13], vals[14], vals[15]);
}

// ---------------------------------------------------------------------------
extern "C" void kernel_launch(void* const* d_in, const int* in_sizes, int n_in,
                              void* d_out, int out_size, void* d_ws, size_t ws_size,
                              hipStream_t stream) {
    const float* PHI_S = (const float*)d_in[0];
    const float* Y_S   = (const float*)d_in[1];
    const float* PHI_Q = (const float*)d_in[2];
    const float* Y_Q   = (const float*)d_in[3];
    const float* MP    = (const float*)d_in[4];
    const float* AP    = (const float*)d_in[5];
    const float* SE    = (const float*)d_in[6];
    float* out = (float*)d_out;

    // Big scratch inside sig region of d_out (dead before k_sig runs last).
    double* scratch = (double*)(out + MU_SIZE);
    double* G    = scratch;                    // 8,388,608 dbl (64 MB)
    double* LT   = G + 8388608;                // 8,388,608 dbl
    double* RHS  = LT + 8388608;               // 2,097,152 dbl (-> becomes M)
    double* Z    = RHS + 2097152;              // 2,097,152 dbl
    double* TI   = Z + 2097152;                // 8,388,608 dbl
    double* Spd  = TI + 8388608;               // 65,536 dbl
    double* MPN  = Spd + 65536;                // 16,384 dbl
    double* LI   = MPN + 16384;                // 2,097,152 dbl (16 MB, L11inv)
    float*  TIF  = (float*)(LI + 2097152);     // 8,388,608 f32 (32 MB)
    float*  PSUM = TIF + 8388608;              // 262,144 f32 (1 MB)
    // Small persistent scratch (survives until k_sig) in d_ws (proven 258 KB).
    float*  SPREAD = (float*)d_ws;                         // 65,536 f32
    double* NLLACC = (double*)((char*)d_ws + 65536 * 4);   // 1 dbl
    double* FLAGD  = (double*)((char*)d_ws + 65536 * 4 + 8); // 1 dbl

    k_mfma_probe <<<1, 64, 0, stream>>>(FLAGD);
    k_prior_sp   <<<256, 256, 0, stream>>>(AP, Spd, NLLACC);
    k_prior_mpn  <<<256, 64, 0, stream>>>(Spd, MP, MPN);
    k_build_G    <<<dim3(B_T, 10), 256, 0, stream>>>(PHI_S, Spd, G, FLAGD);
    k_build_rhs  <<<dim3(B_T, 4), 256, 0, stream>>>(PHI_S, Y_S, MPN, RHS, FLAGD);
    // blocked Cholesky at grid level, NB=64
    const int syrk_pairs[3] = {6, 3, 1};
    for (int kb = 0; kb < 4; ++kb) {
        k_potrf64<<<B_T, 256, 0, stream>>>(G, LT, LI, kb);
        if (kb < 3) {
            k_trsm64<<<dim3(B_T, 3 - kb), 256, 0, stream>>>(G, LI, LT, kb, FLAGD);
            k_syrk64<<<dim3(B_T, syrk_pairs[kb]), 256, 0, stream>>>(LT, G, kb, FLAGD);
        }
    }
    k_diaginv    <<<B_T, 256, 0, stream>>>(LT, TI, TIF);
    k_trinv      <<<dim3(B_T, 7), 256, 0, stream>>>(LT, TI, TIF);
    k_gemm_Z     <<<dim3(B_T, 4), 256, 0, stream>>>(TI, RHS, Z, FLAGD);
    k_gemm_M     <<<dim3(B_T, 4), 256, 0, stream>>>(TI, Z, RHS, FLAGD);
    k_spread_gemm<<<dim3(B_T, 8, 4), 256, 0, stream>>>(PHI_Q, TIF, PSUM);
    k_mu_nll     <<<dim3(B_T, 8), 256, 0, stream>>>(PHI_Q, RHS, Y_Q, PSUM, SE,
                                                    SPREAD, NLLACC, out);
    k_nll_final  <<<1, 64, 0, stream>>>(NLLACC, out);
    k_sig        <<<65536, 256, 0, stream>>>(SPREAD, SE, out);   // LAST
}